// Round 16
// baseline (429.108 us; speedup 1.0000x reference)
//
#include <hip/hip_runtime.h>
#include <cmath>

#define NNODES 32768
#define NEDGES 524288
#define NBATCH 16
#define NSAMP  2048
#define EPS    1e-5f

#define PK2 72    // 64 + 8 pad (shorts); row stride 144 B (16B-multiple)

typedef short s16x8 __attribute__((ext_vector_type(8)));
typedef float f32x4 __attribute__((ext_vector_type(4)));
typedef unsigned short ushort_t;

struct YArr { float v[192]; };

static __device__ __forceinline__ unsigned short f2bf(float f) {
  unsigned int u = __float_as_uint(f);
  u = (u + 0x7fffu + ((u >> 16) & 1u)) >> 16;   // RN-even
  return (unsigned short)u;
}
static __device__ __forceinline__ float bf2f(unsigned short b) {
  return __uint_as_float(((unsigned int)b) << 16);
}

// pack two f32 into bf16 hi-pair + residual lo-pair via HW cvt_pk (1 instr per pair)
// ph = [bf16(v1) | bf16(v0)], pl = [bf16(v1-h1) | bf16(v0-h0)]
static __device__ __forceinline__ void pack2(float v0, float v1,
                                             unsigned int& ph, unsigned int& pl) {
  asm("v_cvt_pk_bf16_f32 %0, %1, %2" : "=v"(ph) : "v"(v0), "v"(v1));
  float h0 = __uint_as_float(ph << 16);
  float h1 = __uint_as_float(ph & 0xffff0000u);
  asm("v_cvt_pk_bf16_f32 %0, %1, %2" : "=v"(pl) : "v"(v0 - h0), "v"(v1 - h1));
}

// ------------- setup: weight prep (blocks 0..383) + CSR count (blocks 384..) ----
__global__ __launch_bounds__(256) void setup_kernel(
    const float* __restrict__ m1W, const float* __restrict__ m2W,
    const float* __restrict__ u1W, const float* __restrict__ u2W,
    ushort_t* __restrict__ wc_hi, ushort_t* __restrict__ wc_lo,
    ushort_t* __restrict__ w1b_hi, ushort_t* __restrict__ w1b_lo,
    ushort_t* __restrict__ w2e_hi, ushort_t* __restrict__ w2e_lo,
    ushort_t* __restrict__ w2n_hi, ushort_t* __restrict__ w2n_lo,
    const int* __restrict__ edst, int* __restrict__ cnt)
{
  if (blockIdx.x >= 384) {
    int e = (blockIdx.x - 384) * 256 + threadIdx.x;
    if (e < NEDGES) atomicAdd(&cnt[edst[e]], 1);
    return;
  }
  int t = blockIdx.x * 256 + threadIdx.x;
  if (t >= 4 * 24576) return;
  int l = t / 24576;
  int r = t % 24576;
  float w; ushort_t *dh, *dl;
  if (r < 12288) {                      // Wcomb: P|Q|R
    int j = r >> 6, k = r & 63;
    if (j < 64)       w = m1W[l*8192 + k*64 + j];
    else if (j < 128) w = m1W[l*8192 + (64 + k)*64 + (j - 64)];
    else              w = u1W[l*8192 + k*64 + (j - 128)];
    int off = l*192*PK2 + j*PK2 + k;
    dh = wc_hi + off; dl = wc_lo + off;
  } else if (r < 16384) {               // W1b
    int idx = r - 12288;
    int j = idx & 63, k = idx >> 6;
    w = u1W[l*8192 + (64 + k)*64 + j];
    int off = l*64*PK2 + j*PK2 + k;
    dh = w1b_hi + off; dl = w1b_lo + off;
  } else if (r < 20480) {               // W2e
    int idx = r - 16384;
    int j = idx & 63, k = idx >> 6;
    w = m2W[l*4096 + k*64 + j];
    int off = l*64*PK2 + j*PK2 + k;
    dh = w2e_hi + off; dl = w2e_lo + off;
  } else {                              // W2n
    int idx = r - 20480;
    int j = idx & 63, k = idx >> 6;
    w = u2W[l*4096 + k*64 + j];
    int off = l*64*PK2 + j*PK2 + k;
    dh = w2n_hi + off; dl = w2n_lo + off;
  }
  unsigned short hb = f2bf(w);
  *dh = hb;
  *dl = f2bf(w - bf2f(hb));
}

__global__ __launch_bounds__(1024) void scan_kernel(const int* __restrict__ cnt,
                                                    int* __restrict__ offs,
                                                    int* __restrict__ cursor) {
  __shared__ int sc[1024];
  int tid = threadIdx.x;
  int base = tid * 32;
  int s = 0;
  #pragma unroll
  for (int i = 0; i < 32; i++) s += cnt[base + i];
  sc[tid] = s; __syncthreads();
  int own = s;
  for (int off = 1; off < 1024; off <<= 1) {
    int v = (tid >= off) ? sc[tid - off] : 0;
    __syncthreads();
    sc[tid] += v;
    __syncthreads();
  }
  int run = sc[tid] - own;
  for (int i = 0; i < 32; i++) {
    offs[base + i] = run; cursor[base + i] = run;
    run += cnt[base + i];
  }
}

__global__ __launch_bounds__(256) void fill_kernel(
    const int* __restrict__ esrc, const int* __restrict__ edst,
    int* __restrict__ cursor, int* __restrict__ psrc, int* __restrict__ pdst) {
  int e = blockIdx.x * 256 + threadIdx.x;
  if (e < NEDGES) {
    int d = edst[e];
    int pos = atomicAdd(&cursor[d], 1);
    psrc[pos] = esrc[e];
    pdst[pos] = d;
  }
}

// ------------- fused (encode|norm) + P|Q|R GEMM -------------
template<int MODE>
__global__ __launch_bounds__(256) void norm_pqr_kernel(
    const float* __restrict__ in,     // x (MODE 0) or u (MODE 1)
    const float* __restrict__ sA, const float* __restrict__ sB,
    const float* __restrict__ encW, const float* __restrict__ encb,
    const ushort_t* __restrict__ Wh, const ushort_t* __restrict__ Wl,
    float* __restrict__ P, float* __restrict__ Q, float* __restrict__ Rb)
{
  __shared__ __align__(16) ushort_t sAh[4][16*PK2];
  __shared__ __align__(16) ushort_t sAl[4][16*PK2];
  int tid = threadIdx.x, lane = tid & 63, wave = tid >> 6;
  int l15 = lane & 15, quad = lane >> 4;
  int base = blockIdx.x * 64 + wave * 16;
  int g = blockIdx.x >> 5;

  float mean = 0.f, rstd = 1.f, w0 = 0.f, w1 = 0.f, w2 = 0.f, bb = 0.f;
  if (MODE) {
    float a = sA[g*64 + lane], q = sB[g*64 + lane];
    mean = a * (1.f / NSAMP);
    float var = q * (1.f / NSAMP) - mean * mean;
    rstd = rsqrtf(var + EPS);
  } else {
    w0 = encW[lane]; w1 = encW[64 + lane]; w2 = encW[128 + lane];
    bb = encb[lane];
  }

  ushort_t* ah_s = sAh[wave];
  ushort_t* al_s = sAl[wave];
  #pragma unroll
  for (int r = 0; r < 16; r += 2) {
    int n = base + r;
    float v0, v1;
    if (MODE) {
      v0 = (in[(size_t)n*64 + lane] - mean) * rstd;
      v1 = (in[(size_t)(n+1)*64 + lane] - mean) * rstd;
    } else {
      v0 = fmaf(in[n*3+2], w2, fmaf(in[n*3+1], w1, fmaf(in[n*3+0], w0, bb)));
      v1 = fmaf(in[(n+1)*3+2], w2, fmaf(in[(n+1)*3+1], w1, fmaf(in[(n+1)*3+0], w0, bb)));
    }
    unsigned int ph, pl;
    pack2(v0, v1, ph, pl);
    ah_s[r*PK2 + lane]     = (ushort_t)(ph & 0xffffu);
    ah_s[(r+1)*PK2 + lane] = (ushort_t)(ph >> 16);
    al_s[r*PK2 + lane]     = (ushort_t)(pl & 0xffffu);
    al_s[(r+1)*PK2 + lane] = (ushort_t)(pl >> 16);
  }

  s16x8 ah[2], al[2];
  #pragma unroll
  for (int kb = 0; kb < 2; kb++) {
    int idx = l15*PK2 + kb*32 + quad*8;
    ah[kb] = *(const s16x8*)&ah_s[idx];
    al[kb] = *(const s16x8*)&al_s[idx];
  }

  #pragma unroll
  for (int ct = 0; ct < 12; ct++) {
    f32x4 acc = (f32x4){0.f, 0.f, 0.f, 0.f};
    #pragma unroll
    for (int kb = 0; kb < 2; kb++) {
      int woff = (ct*16 + l15)*PK2 + kb*32 + quad*8;
      s16x8 bh = *(const s16x8*)(Wh + woff);
      s16x8 bl = *(const s16x8*)(Wl + woff);
      // bf16x3: drop al*bl (≤2^-18 relative ≈ 4e-6 per term)
      acc = __builtin_amdgcn_mfma_f32_16x16x32_bf16(al[kb], bh, acc, 0, 0, 0);
      acc = __builtin_amdgcn_mfma_f32_16x16x32_bf16(ah[kb], bl, acc, 0, 0, 0);
      acc = __builtin_amdgcn_mfma_f32_16x16x32_bf16(ah[kb], bh, acc, 0, 0, 0);
    }
    int j = ct*16 + l15;
    float* dst; int jj;
    if (ct < 4)      { dst = P;  jj = j; }
    else if (ct < 8) { dst = Q;  jj = j - 64; }
    else             { dst = Rb; jj = j - 128; }
    #pragma unroll
    for (int rr = 0; rr < 4; rr++) {
      int row = base + quad*4 + rr;
      dst[(size_t)row*64 + jj] = acc[rr];
    }
  }
}

// ------------- fused edge MLP + segment-reduce (grid 768) --------
// R13: cross-tile pipeline — double-buffered sSD; next tile's index write +
//      group-0 gathers issued right after MFMA so they fly during m2+reduce.
__global__ __launch_bounds__(256, 3) void edge_fused_kernel(
    const float* __restrict__ Pbuf, const float* __restrict__ Qbuf,
    const int* __restrict__ psrc, const int* __restrict__ pdst,
    const float* __restrict__ b1,
    const ushort_t* __restrict__ W2hi, const ushort_t* __restrict__ W2lo,
    const float* __restrict__ b2,
    float* __restrict__ agg)
{
  __shared__ __align__(16) char smem[4][9216];
  __shared__ int  sSDb[2][4][64];

  int tid = threadIdx.x;
  int lane = tid & 63, wave = tid >> 6;
  int l15 = lane & 15, quad = lane >> 4;

  ushort_t* mh = (ushort_t*)smem[wave];
  ushort_t* ml = mh + 32*PK2;
  float*    m2 = (float*)smem[wave];

  s16x8 w2h[2][4], w2l[2][4];
  #pragma unroll
  for (int kb = 0; kb < 2; kb++)
    #pragma unroll
    for (int ct = 0; ct < 4; ct++) {
      int off = (ct*16 + l15)*PK2 + kb*32 + quad*8;
      w2h[kb][ct] = *(const s16x8*)(W2hi + off);
      w2l[kb][ct] = *(const s16x8*)(W2lo + off);
    }
  float b1v = b1[lane];
  float b2v[4];
  #pragma unroll
  for (int ct = 0; ct < 4; ct++) b2v[ct] = b2[ct*16 + l15];

  const int* tb = (lane < 32) ? psrc : pdst;
  int lidx = lane & 31;
  int step = gridDim.x * 128;
  int base0 = blockIdx.x * 128;

  // prologue: tile-0 indices + its group-0 gathers
  int sidx = tb[base0 + wave*32 + lidx];
  sSDb[0][wave][lane] = sidx;

  float pv[2][8], qv[2][8];
  #pragma unroll
  for (int i = 0; i < 8; i++) {
    int s = sSDb[0][wave][i];
    int d = sSDb[0][wave][32 + i];
    qv[0][i] = Qbuf[((size_t)s << 6) + lane];
    pv[0][i] = Pbuf[((size_t)d << 6) + lane];
  }

  int cb = 0;
  for (int base = base0; base < NEDGES; base += step) {
    const int* sc = sSDb[cb][wave];
    int nb = base + step;
    int havenext = nb < NEDGES;
    if (havenext) sidx = tb[nb + wave*32 + lidx];   // index prefetch (returns well before use)

    // intra-tile pipelined gather: pack rb from buf[rb&1], gather rb+1 into other
    #pragma unroll
    for (int rb = 0; rb < 4; rb++) {
      int cur = rb & 1;
      if (rb < 3) {
        #pragma unroll
        for (int i = 0; i < 8; i++) {
          int r = (rb+1)*8 + i;
          qv[cur^1][i] = Qbuf[((size_t)sc[r] << 6) + lane];
          pv[cur^1][i] = Pbuf[((size_t)sc[32 + r] << 6) + lane];
        }
      }
      #pragma unroll
      for (int i = 0; i < 8; i += 2) {
        int r = rb*8 + i;
        float v0 = fmaxf(pv[cur][i]   + qv[cur][i]   + b1v, 0.f);
        float v1 = fmaxf(pv[cur][i+1] + qv[cur][i+1] + b1v, 0.f);
        unsigned int ph, pl;
        pack2(v0, v1, ph, pl);
        mh[r*PK2 + lane]     = (ushort_t)(ph & 0xffffu);
        mh[(r+1)*PK2 + lane] = (ushort_t)(ph >> 16);
        ml[r*PK2 + lane]     = (ushort_t)(pl & 0xffffu);
        ml[(r+1)*PK2 + lane] = (ushort_t)(pl >> 16);
      }
    }

    f32x4 facc[2][4];
    #pragma unroll
    for (int rt = 0; rt < 2; rt++)
      #pragma unroll
      for (int ct = 0; ct < 4; ct++)
        facc[rt][ct] = (f32x4){0.f, 0.f, 0.f, 0.f};

    #pragma unroll
    for (int kb = 0; kb < 2; kb++) {
      s16x8 mhf[2], mlf[2];
      #pragma unroll
      for (int rt = 0; rt < 2; rt++) {
        int idx = (rt*16 + l15)*PK2 + kb*32 + quad*8;
        mhf[rt] = *(const s16x8*)&mh[idx];
        mlf[rt] = *(const s16x8*)&ml[idx];
      }
      #pragma unroll
      for (int ct = 0; ct < 4; ct++)
        #pragma unroll
        for (int rt = 0; rt < 2; rt++) {
          // bf16x3: drop ml*w2l
          facc[rt][ct] = __builtin_amdgcn_mfma_f32_16x16x32_bf16(mlf[rt], w2h[kb][ct], facc[rt][ct], 0, 0, 0);
          facc[rt][ct] = __builtin_amdgcn_mfma_f32_16x16x32_bf16(mhf[rt], w2l[kb][ct], facc[rt][ct], 0, 0, 0);
          facc[rt][ct] = __builtin_amdgcn_mfma_f32_16x16x32_bf16(mhf[rt], w2h[kb][ct], facc[rt][ct], 0, 0, 0);
        }
    }

    // cross-tile prefetch: stage next tile's indices + issue its group-0
    // gathers NOW so they are in flight during m2-write + reduce + atomics.
    if (havenext) {
      int* sn = sSDb[cb ^ 1][wave];
      sn[lane] = sidx;
      #pragma unroll
      for (int i = 0; i < 8; i++) {
        qv[0][i] = Qbuf[((size_t)sn[i] << 6) + lane];
        pv[0][i] = Pbuf[((size_t)sn[32 + i] << 6) + lane];
      }
    }

    #pragma unroll
    for (int rt = 0; rt < 2; rt++)
      #pragma unroll
      for (int ct = 0; ct < 4; ct++)
        #pragma unroll
        for (int r = 0; r < 4; r++)
          m2[(rt*16 + quad*4 + r)*68 + ct*16 + l15] = fmaxf(facc[rt][ct][r] + b2v[ct], 0.f);

    // serial 32-row segment reduce (measured-good form)
    int curd = sc[32];
    float acc = 0.f;
    #pragma unroll
    for (int r = 0; r < 32; r++) {
      int d = sc[32 + r];
      float v = m2[r*68 + lane];
      if (d != curd) {
        unsafeAtomicAdd(&agg[((size_t)curd << 6) + lane], acc);
        acc = 0.f; curd = d;
      }
      acc += v;
    }
    unsafeAtomicAdd(&agg[((size_t)curd << 6) + lane], acc);

    cb ^= 1;
  }
}

// ------------- node MLP -------------
__global__ __launch_bounds__(256) void node_mfma_kernel(
    const float* __restrict__ aggF, const float* __restrict__ Rbuf,
    const ushort_t* __restrict__ W1h, const ushort_t* __restrict__ W1l,
    const float* __restrict__ b1,
    const ushort_t* __restrict__ W2h, const ushort_t* __restrict__ W2l,
    const float* __restrict__ b2,
    float* __restrict__ uout, float* __restrict__ sA, float* __restrict__ sB)
{
  __shared__ __align__(16) ushort_t sMh[4][16*PK2];
  __shared__ __align__(16) ushort_t sMl[4][16*PK2];
  int tid = threadIdx.x, lane = tid & 63, wave = tid >> 6;
  int l15 = lane & 15, quad = lane >> 4;
  int base = blockIdx.x * 64 + wave * 16;
  int g = blockIdx.x >> 5;

  s16x8 ah[2], al[2];
  {
    int em = base + l15;
    #pragma unroll
    for (int kb = 0; kb < 2; kb++) {
      size_t off = (size_t)em*64 + kb*32 + quad*8;
      float4 v0 = *(const float4*)(aggF + off);
      float4 v1 = *(const float4*)(aggF + off + 4);
      float vv[8] = {v0.x,v0.y,v0.z,v0.w,v1.x,v1.y,v1.z,v1.w};
      s16x8 hh, ll;
      #pragma unroll
      for (int j = 0; j < 8; j += 2) {
        unsigned int ph, pl;
        pack2(vv[j], vv[j+1], ph, pl);
        hh[j]   = (short)(ph & 0xffffu);
        hh[j+1] = (short)(ph >> 16);
        ll[j]   = (short)(pl & 0xffffu);
        ll[j+1] = (short)(pl >> 16);
      }
      ah[kb] = hh; al[kb] = ll;
    }
  }

  ushort_t* mh = sMh[wave];
  ushort_t* ml = sMl[wave];
  float b1v[4], b2v[4];
  #pragma unroll
  for (int ct = 0; ct < 4; ct++) { b1v[ct] = b1[ct*16+l15]; b2v[ct] = b2[ct*16+l15]; }

  #pragma unroll
  for (int ct = 0; ct < 4; ct++) {
    f32x4 acc = (f32x4){0.f, 0.f, 0.f, 0.f};
    #pragma unroll
    for (int kb = 0; kb < 2; kb++) {
      int woff = (ct*16 + l15)*PK2 + kb*32 + quad*8;
      s16x8 bh = *(const s16x8*)(W1h + woff);
      s16x8 bl = *(const s16x8*)(W1l + woff);
      // bf16x3: drop al*bl
      acc = __builtin_amdgcn_mfma_f32_16x16x32_bf16(al[kb], bh, acc, 0, 0, 0);
      acc = __builtin_amdgcn_mfma_f32_16x16x32_bf16(ah[kb], bl, acc, 0, 0, 0);
      acc = __builtin_amdgcn_mfma_f32_16x16x32_bf16(ah[kb], bh, acc, 0, 0, 0);
    }
    int j = ct*16 + l15;
    #pragma unroll
    for (int rr = 0; rr < 4; rr += 2) {
      int row = quad*4 + rr;
      float v0 = fmaxf(acc[rr]   + Rbuf[(size_t)(base+row)*64   + j] + b1v[ct], 0.f);
      float v1 = fmaxf(acc[rr+1] + Rbuf[(size_t)(base+row+1)*64 + j] + b1v[ct], 0.f);
      unsigned int ph, pl;
      pack2(v0, v1, ph, pl);
      mh[row*PK2 + j]     = (ushort_t)(ph & 0xffffu);
      mh[(row+1)*PK2 + j] = (ushort_t)(ph >> 16);
      ml[row*PK2 + j]     = (ushort_t)(pl & 0xffffu);
      ml[(row+1)*PK2 + j] = (ushort_t)(pl >> 16);
    }
  }

  s16x8 mhf[2], mlf[2];
  #pragma unroll
  for (int kb = 0; kb < 2; kb++) {
    int idx = l15*PK2 + kb*32 + quad*8;
    mhf[kb] = *(const s16x8*)&mh[idx];
    mlf[kb] = *(const s16x8*)&ml[idx];
  }
  #pragma unroll
  for (int ct = 0; ct < 4; ct++) {
    f32x4 facc = (f32x4){0.f, 0.f, 0.f, 0.f};
    #pragma unroll
    for (int kb = 0; kb < 2; kb++) {
      int woff = (ct*16 + l15)*PK2 + kb*32 + quad*8;
      s16x8 bh = *(const s16x8*)(W2h + woff);
      s16x8 bl = *(const s16x8*)(W2l + woff);
      // bf16x3: drop mlf*bl
      facc = __builtin_amdgcn_mfma_f32_16x16x32_bf16(mlf[kb], bh, facc, 0, 0, 0);
      facc = __builtin_amdgcn_mfma_f32_16x16x32_bf16(mhf[kb], bl, facc, 0, 0, 0);
      facc = __builtin_amdgcn_mfma_f32_16x16x32_bf16(mhf[kb], bh, facc, 0, 0, 0);
    }
    int j = ct*16 + l15;
    float s = 0.f, s2 = 0.f;
    #pragma unroll
    for (int rr = 0; rr < 4; rr++) {
      int row = quad*4 + rr;
      float v = fmaxf(facc[rr] + b2v[ct], 0.f);
      uout[(size_t)(base+row)*64 + j] = v;
      s += v; s2 += v*v;
    }
    s  += __shfl_xor(s, 16);  s  += __shfl_xor(s, 32);
    s2 += __shfl_xor(s2, 16); s2 += __shfl_xor(s2, 32);
    if (quad == 0) {
      unsafeAtomicAdd(&sA[g*64 + j], s);
      unsafeAtomicAdd(&sB[g*64 + j], s2);
    }
  }
}

// ------------- decoder -------------
__global__ __launch_bounds__(64) void decoder_kernel(
    const float* __restrict__ u, const float* __restrict__ sA,
    const float* __restrict__ sB, const float* __restrict__ W,
    const float* __restrict__ b, float* __restrict__ X)
{
  __shared__ float sh[64][65];
  __shared__ float sm[64], sr[64];
  int lane = threadIdx.x;
  int nb = blockIdx.x * 64;
  int g = blockIdx.x >> 5;
  {
    float a = sA[g*64 + lane], q = sB[g*64 + lane];
    float mean = a * (1.f / NSAMP);
    float var = q * (1.f / NSAMP) - mean * mean;
    sm[lane] = mean;
    sr[lane] = rsqrtf(var + EPS);
  }
  for (int r = 0; r < 64; r++) sh[r][lane] = u[(size_t)(nb + r) * 64 + lane];
  __syncthreads();
  float a0 = b[0], a1 = b[1], a2 = b[2];
  #pragma unroll
  for (int c = 0; c < 64; c++) {
    float v = (sh[lane][c] - sm[c]) * sr[c];
    a0 = fmaf(v, W[c*3+0], a0);
    a1 = fmaf(v, W[c*3+1], a1);
    a2 = fmaf(v, W[c*3+2], a2);
  }
  float inv = 1.f / sqrtf(a0*a0 + a1*a1 + a2*a2);
  int n = nb + lane;
  X[n*3+0] = a0 * inv;
  X[n*3+1] = a1 * inv;
  X[n*3+2] = a2 * inv;
}

// ------------- MMD: R14 split 4x for occupancy --------------------
// kXX: 2048 blocks = 16 graphs x 32 n-tiles x 4 m-splits (each: 512 m-points)
// kXY: 64 blocks   = 16 graphs x 4 n-splits              (each: 512 n-points)
__device__ inline float block_reduce_sum(float v) {
  #pragma unroll
  for (int o = 32; o > 0; o >>= 1) v += __shfl_down(v, o, 64);
  __shared__ float red[4];
  int lane = threadIdx.x & 63, w = threadIdx.x >> 6;
  if (lane == 0) red[w] = v;
  __syncthreads();
  float t = 0.f;
  if (threadIdx.x == 0) t = red[0] + red[1] + red[2] + red[3];
  return t;
}

__global__ __launch_bounds__(256) void mmd_kernel(
    const float* __restrict__ X, YArr Y,
    float* __restrict__ kxx, float* __restrict__ kxy)
{
  if (blockIdx.x < 2048) {
    int t  = blockIdx.x;
    int b  = t >> 7;            // / 128 (32 tiles * 4 splits)
    int rem = t & 127;
    int nt = rem >> 2;          // n-tile 0..31
    int ms = rem & 3;           // m-split 0..3
    const float* Xb = X + (size_t)b * NSAMP * 3;
    __shared__ float sx[192];
    if (threadIdx.x < 192) sx[threadIdx.x] = Xb[nt*192 + threadIdx.x];
    __syncthreads();
    float ps = 0.f;
    #pragma unroll
    for (int it = 0; it < 2; it++) {
      int m = ms*512 + it*256 + threadIdx.x;
      float x0 = Xb[m*3+0], x1 = Xb[m*3+1], x2 = Xb[m*3+2];
      #pragma unroll
      for (int n = 0; n < 64; n++) {
        float d = x0*sx[n*3+0] + x1*sx[n*3+1] + x2*sx[n*3+2];
        ps += __expf(2.f*d - 2.f);
      }
    }
    float t2 = block_reduce_sum(ps);
    if (threadIdx.x == 0) atomicAdd(&kxx[b], t2);
  } else {
    int t  = blockIdx.x - 2048;
    int b  = t >> 2;
    int ms = t & 3;
    const float* Xb = X + (size_t)b * NSAMP * 3;
    float ps = 0.f;
    #pragma unroll
    for (int it = 0; it < 2; it++) {
      int n = ms*512 + it*256 + threadIdx.x;
      float x0 = Xb[n*3+0], x1 = Xb[n*3+1], x2 = Xb[n*3+2];
      #pragma unroll
      for (int m = 0; m < 64; m++) {
        float d = x0*Y.v[m*3+0] + x1*Y.v[m*3+1] + x2*Y.v[m*3+2];
        ps += __expf(2.f*d - 2.f);
      }
    }
    float t2 = block_reduce_sum(ps);
    if (threadIdx.x == 0) atomicAdd(&kxy[b], t2);
  }
}

__global__ void loss_kernel(const float* __restrict__ kxx,
                            const float* __restrict__ kxy,
                            float kyy, float* __restrict__ out)
{
  if (threadIdx.x == 0 && blockIdx.x == 0) {
    float s = 0.f;
    for (int b = 0; b < NBATCH; b++)
      s += kxx[b] * (1.0f/((float)NSAMP*(float)NSAMP))
         - 2.0f * kxy[b] * (1.0f/((float)NSAMP*64.0f));
    out[0] = s * (1.0f/NBATCH) + kyy;
  }
}

// ------------- launch -------------
extern "C" void kernel_launch(void* const* d_in, const int* in_sizes, int n_in,
                              void* d_out, int out_size, void* d_ws, size_t ws_size,
                              hipStream_t stream)
{
  const float* x    = (const float*)d_in[0];
  const int*   esrc = (const int*)  d_in[1];
  const int*   edst = (const int*)  d_in[2];
  const float* encW = (const float*)d_in[4];
  const float* encb = (const float*)d_in[5];
  const float* m1W  = (const float*)d_in[6];
  const float* m1b  = (const float*)d_in[7];
  const float* m2W  = (const float*)d_in[8];
  const float* m2b  = (const float*)d_in[9];
  const float* u1W  = (const float*)d_in[10];
  const float* u1b  = (const float*)d_in[11];
  const float* u2W  = (const float*)d_in[12];
  const float* u2b  = (const float*)d_in[13];
  const float* decW = (const float*)d_in[14];
  const float* decb = (const float*)d_in[15];
  float* out = (float*)d_out;

  const size_t NF = (size_t)NNODES * 64;
  // single zero region: [aggAll | statsA | statsB | kxx | kxy | icnt]
  float* aggAll = (float*)d_ws;        // 4 * NF
  float* statsA = aggAll + 4*NF;       // 4096
  float* statsB = statsA + 4096;       // 4096
  float* kxx    = statsB + 4096;       // 16
  float* kxy    = kxx + 16;            // 16 (now zeroed; atomicAdd target)
  int*   icnt   = (int*)(kxy + 16);    // 32768
  size_t zero_bytes = (4*NF + 4096 + 4096 + 32) * sizeof(float) + NNODES * sizeof(int);

  float* u_buf  = (float*)(icnt + NNODES);
  float* Pbuf   = u_buf + NF;
  float* Qbuf   = Pbuf + NF;
  float* Rbuf   = Qbuf + NF;
  int* ioffs    = (int*)(Rbuf + NF + 16);   // +16 pad keeps legacy layout offsets
  int* icur     = ioffs + NNODES;
  int* psrc     = icur + NNODES;
  int* pdst     = psrc + NEDGES;
  ushort_t* us  = (ushort_t*)(pdst + NEDGES);
  ushort_t* wc_hi  = us;  us += 4*192*PK2;
  ushort_t* wc_lo  = us;  us += 4*192*PK2;
  ushort_t* w1b_hi = us;  us += 4*64*PK2;
  ushort_t* w1b_lo = us;  us += 4*64*PK2;
  ushort_t* w2e_hi = us;  us += 4*64*PK2;
  ushort_t* w2e_lo = us;  us += 4*64*PK2;
  ushort_t* w2n_hi = us;  us += 4*64*PK2;
  ushort_t* w2n_lo = us;  us += 4*64*PK2;

  float* X = out + 1;

  hipMemsetAsync(aggAll, 0, zero_bytes, stream);

  setup_kernel<<<384 + NEDGES/256, 256, 0, stream>>>(
      m1W, m2W, u1W, u2W,
      wc_hi, wc_lo, w1b_hi, w1b_lo, w2e_hi, w2e_lo, w2n_hi, w2n_lo,
      edst, icnt);
  scan_kernel<<<1, 1024, 0, stream>>>(icnt, ioffs, icur);
  fill_kernel<<<NEDGES/256, 256, 0, stream>>>(esrc, edst, icur, psrc, pdst);

  for (int l = 0; l < 4; l++) {
    const ushort_t* wch = wc_hi + (size_t)l*192*PK2;
    const ushort_t* wcl = wc_lo + (size_t)l*192*PK2;
    if (l == 0)
      norm_pqr_kernel<0><<<512, 256, 0, stream>>>(
          x, nullptr, nullptr, encW, encb, wch, wcl, Pbuf, Qbuf, Rbuf);
    else
      norm_pqr_kernel<1><<<512, 256, 0, stream>>>(
          u_buf, statsA + (l-1)*1024, statsB + (l-1)*1024, nullptr, nullptr,
          wch, wcl, Pbuf, Qbuf, Rbuf);

    edge_fused_kernel<<<768, 256, 0, stream>>>(
        Pbuf, Qbuf, psrc, pdst, m1b + l*64,
        w2e_hi + (size_t)l*64*PK2, w2e_lo + (size_t)l*64*PK2, m2b + l*64,
        aggAll + (size_t)l*NF);

    node_mfma_kernel<<<512, 256, 0, stream>>>(
        aggAll + (size_t)l*NF, Rbuf,
        w1b_hi + (size_t)l*64*PK2, w1b_lo + (size_t)l*64*PK2, u1b + l*64,
        w2n_hi + (size_t)l*64*PK2, w2n_lo + (size_t)l*64*PK2, u2b + l*64,
        u_buf, statsA + l*1024, statsB + l*1024);
  }

  decoder_kernel<<<NNODES/64, 64, 0, stream>>>(
      u_buf, statsA + 3*1024, statsB + 3*1024, decW, decb, X);

  YArr Y;
  {
    const double pi = 3.14159265358979323846;
    double phi = pi * (3.0 - sqrt(5.0));
    for (int i = 0; i < 64; i++) {
      double y  = 1.0 - 2.0 * (double)i / 63.0;
      double r  = sqrt(fmax(0.0, 1.0 - y*y));
      double th = phi * (double)i;
      Y.v[i*3+0] = (float)(cos(th) * r);
      Y.v[i*3+1] = (float)y;
      Y.v[i*3+2] = (float)(sin(th) * r);
    }
  }
  double kyy_acc = 0.0;
  for (int i = 0; i < 64; i++)
    for (int j = 0; j < 64; j++) {
      double d = (double)Y.v[i*3+0]*Y.v[j*3+0]
               + (double)Y.v[i*3+1]*Y.v[j*3+1]
               + (double)Y.v[i*3+2]*Y.v[j*3+2];
      kyy_acc += exp(2.0*d - 2.0);
    }
  float kyy = (float)(kyy_acc / 4096.0);

  mmd_kernel<<<2048 + 64, 256, 0, stream>>>(X, Y, kxx, kxy);
  loss_kernel<<<1, 64, 0, stream>>>(kxx, kxy, kyy, out);
}

// Round 17
// 415.909 us; speedup vs baseline: 1.0317x; 1.0317x over previous
//
#include <hip/hip_runtime.h>
#include <cmath>

#define NNODES 32768
#define NEDGES 524288
#define NBATCH 16
#define NSAMP  2048
#define EPS    1e-5f

#define PK2 72    // 64 + 8 pad (shorts); row stride 144 B (16B-multiple)

typedef short s16x8 __attribute__((ext_vector_type(8)));
typedef float f32x4 __attribute__((ext_vector_type(4)));
typedef unsigned short ushort_t;

struct YArr { float v[192]; };

static __device__ __forceinline__ unsigned short f2bf(float f) {
  unsigned int u = __float_as_uint(f);
  u = (u + 0x7fffu + ((u >> 16) & 1u)) >> 16;   // RN-even
  return (unsigned short)u;
}
static __device__ __forceinline__ float bf2f(unsigned short b) {
  return __uint_as_float(((unsigned int)b) << 16);
}

// pack two f32 into bf16 hi-pair + residual lo-pair via HW cvt_pk (1 instr per pair)
// ph = [bf16(v1) | bf16(v0)], pl = [bf16(v1-h1) | bf16(v0-h0)]
static __device__ __forceinline__ void pack2(float v0, float v1,
                                             unsigned int& ph, unsigned int& pl) {
  asm("v_cvt_pk_bf16_f32 %0, %1, %2" : "=v"(ph) : "v"(v0), "v"(v1));
  float h0 = __uint_as_float(ph << 16);
  float h1 = __uint_as_float(ph & 0xffff0000u);
  asm("v_cvt_pk_bf16_f32 %0, %1, %2" : "=v"(pl) : "v"(v0 - h0), "v"(v1 - h1));
}

// ------------- setup: weight prep (blocks 0..383) + CSR count (blocks 384..) ----
__global__ __launch_bounds__(256) void setup_kernel(
    const float* __restrict__ m1W, const float* __restrict__ m2W,
    const float* __restrict__ u1W, const float* __restrict__ u2W,
    ushort_t* __restrict__ wc_hi, ushort_t* __restrict__ wc_lo,
    ushort_t* __restrict__ w1b_hi, ushort_t* __restrict__ w1b_lo,
    ushort_t* __restrict__ w2e_hi, ushort_t* __restrict__ w2e_lo,
    ushort_t* __restrict__ w2n_hi, ushort_t* __restrict__ w2n_lo,
    const int* __restrict__ edst, int* __restrict__ cnt)
{
  if (blockIdx.x >= 384) {
    int e = (blockIdx.x - 384) * 256 + threadIdx.x;
    if (e < NEDGES) atomicAdd(&cnt[edst[e]], 1);
    return;
  }
  int t = blockIdx.x * 256 + threadIdx.x;
  if (t >= 4 * 24576) return;
  int l = t / 24576;
  int r = t % 24576;
  float w; ushort_t *dh, *dl;
  if (r < 12288) {                      // Wcomb: P|Q|R
    int j = r >> 6, k = r & 63;
    if (j < 64)       w = m1W[l*8192 + k*64 + j];
    else if (j < 128) w = m1W[l*8192 + (64 + k)*64 + (j - 64)];
    else              w = u1W[l*8192 + k*64 + (j - 128)];
    int off = l*192*PK2 + j*PK2 + k;
    dh = wc_hi + off; dl = wc_lo + off;
  } else if (r < 16384) {               // W1b
    int idx = r - 12288;
    int j = idx & 63, k = idx >> 6;
    w = u1W[l*8192 + (64 + k)*64 + j];
    int off = l*64*PK2 + j*PK2 + k;
    dh = w1b_hi + off; dl = w1b_lo + off;
  } else if (r < 20480) {               // W2e
    int idx = r - 16384;
    int j = idx & 63, k = idx >> 6;
    w = m2W[l*4096 + k*64 + j];
    int off = l*64*PK2 + j*PK2 + k;
    dh = w2e_hi + off; dl = w2e_lo + off;
  } else {                              // W2n
    int idx = r - 20480;
    int j = idx & 63, k = idx >> 6;
    w = u2W[l*4096 + k*64 + j];
    int off = l*64*PK2 + j*PK2 + k;
    dh = w2n_hi + off; dl = w2n_lo + off;
  }
  unsigned short hb = f2bf(w);
  *dh = hb;
  *dl = f2bf(w - bf2f(hb));
}

__global__ __launch_bounds__(1024) void scan_kernel(const int* __restrict__ cnt,
                                                    int* __restrict__ offs,
                                                    int* __restrict__ cursor) {
  __shared__ int sc[1024];
  int tid = threadIdx.x;
  int base = tid * 32;
  int s = 0;
  #pragma unroll
  for (int i = 0; i < 32; i++) s += cnt[base + i];
  sc[tid] = s; __syncthreads();
  int own = s;
  for (int off = 1; off < 1024; off <<= 1) {
    int v = (tid >= off) ? sc[tid - off] : 0;
    __syncthreads();
    sc[tid] += v;
    __syncthreads();
  }
  int run = sc[tid] - own;
  for (int i = 0; i < 32; i++) {
    offs[base + i] = run; cursor[base + i] = run;
    run += cnt[base + i];
  }
}

__global__ __launch_bounds__(256) void fill_kernel(
    const int* __restrict__ esrc, const int* __restrict__ edst,
    int* __restrict__ cursor, int* __restrict__ psrc, int* __restrict__ pdst) {
  int e = blockIdx.x * 256 + threadIdx.x;
  if (e < NEDGES) {
    int d = edst[e];
    int pos = atomicAdd(&cursor[d], 1);
    psrc[pos] = esrc[e];
    pdst[pos] = d;
  }
}

// ------------- fused (encode|norm) + P|Q|R GEMM -------------
template<int MODE>
__global__ __launch_bounds__(256) void norm_pqr_kernel(
    const float* __restrict__ in,     // x (MODE 0) or u (MODE 1)
    const float* __restrict__ sA, const float* __restrict__ sB,
    const float* __restrict__ encW, const float* __restrict__ encb,
    const ushort_t* __restrict__ Wh, const ushort_t* __restrict__ Wl,
    float* __restrict__ P, float* __restrict__ Q, float* __restrict__ Rb)
{
  __shared__ __align__(16) ushort_t sAh[4][16*PK2];
  __shared__ __align__(16) ushort_t sAl[4][16*PK2];
  int tid = threadIdx.x, lane = tid & 63, wave = tid >> 6;
  int l15 = lane & 15, quad = lane >> 4;
  int base = blockIdx.x * 64 + wave * 16;
  int g = blockIdx.x >> 5;

  float mean = 0.f, rstd = 1.f, w0 = 0.f, w1 = 0.f, w2 = 0.f, bb = 0.f;
  if (MODE) {
    float a = sA[g*64 + lane], q = sB[g*64 + lane];
    mean = a * (1.f / NSAMP);
    float var = q * (1.f / NSAMP) - mean * mean;
    rstd = rsqrtf(var + EPS);
  } else {
    w0 = encW[lane]; w1 = encW[64 + lane]; w2 = encW[128 + lane];
    bb = encb[lane];
  }

  ushort_t* ah_s = sAh[wave];
  ushort_t* al_s = sAl[wave];
  #pragma unroll
  for (int r = 0; r < 16; r += 2) {
    int n = base + r;
    float v0, v1;
    if (MODE) {
      v0 = (in[(size_t)n*64 + lane] - mean) * rstd;
      v1 = (in[(size_t)(n+1)*64 + lane] - mean) * rstd;
    } else {
      v0 = fmaf(in[n*3+2], w2, fmaf(in[n*3+1], w1, fmaf(in[n*3+0], w0, bb)));
      v1 = fmaf(in[(n+1)*3+2], w2, fmaf(in[(n+1)*3+1], w1, fmaf(in[(n+1)*3+0], w0, bb)));
    }
    unsigned int ph, pl;
    pack2(v0, v1, ph, pl);
    ah_s[r*PK2 + lane]     = (ushort_t)(ph & 0xffffu);
    ah_s[(r+1)*PK2 + lane] = (ushort_t)(ph >> 16);
    al_s[r*PK2 + lane]     = (ushort_t)(pl & 0xffffu);
    al_s[(r+1)*PK2 + lane] = (ushort_t)(pl >> 16);
  }

  s16x8 ah[2], al[2];
  #pragma unroll
  for (int kb = 0; kb < 2; kb++) {
    int idx = l15*PK2 + kb*32 + quad*8;
    ah[kb] = *(const s16x8*)&ah_s[idx];
    al[kb] = *(const s16x8*)&al_s[idx];
  }

  #pragma unroll
  for (int ct = 0; ct < 12; ct++) {
    f32x4 acc = (f32x4){0.f, 0.f, 0.f, 0.f};
    #pragma unroll
    for (int kb = 0; kb < 2; kb++) {
      int woff = (ct*16 + l15)*PK2 + kb*32 + quad*8;
      s16x8 bh = *(const s16x8*)(Wh + woff);
      s16x8 bl = *(const s16x8*)(Wl + woff);
      // bf16x3: drop al*bl (≤2^-18 relative ≈ 4e-6 per term)
      acc = __builtin_amdgcn_mfma_f32_16x16x32_bf16(al[kb], bh, acc, 0, 0, 0);
      acc = __builtin_amdgcn_mfma_f32_16x16x32_bf16(ah[kb], bl, acc, 0, 0, 0);
      acc = __builtin_amdgcn_mfma_f32_16x16x32_bf16(ah[kb], bh, acc, 0, 0, 0);
    }
    int j = ct*16 + l15;
    float* dst; int jj;
    if (ct < 4)      { dst = P;  jj = j; }
    else if (ct < 8) { dst = Q;  jj = j - 64; }
    else             { dst = Rb; jj = j - 128; }
    #pragma unroll
    for (int rr = 0; rr < 4; rr++) {
      int row = base + quad*4 + rr;
      dst[(size_t)row*64 + jj] = acc[rr];
    }
  }
}

// ------------- fused edge MLP + segment-reduce (grid 768) --------
// R13: cross-tile pipeline — double-buffered sSD; next tile's index write +
//      group-0 gathers issued right after MFMA so they fly during m2+reduce.
__global__ __launch_bounds__(256, 3) void edge_fused_kernel(
    const float* __restrict__ Pbuf, const float* __restrict__ Qbuf,
    const int* __restrict__ psrc, const int* __restrict__ pdst,
    const float* __restrict__ b1,
    const ushort_t* __restrict__ W2hi, const ushort_t* __restrict__ W2lo,
    const float* __restrict__ b2,
    float* __restrict__ agg)
{
  __shared__ __align__(16) char smem[4][9216];
  __shared__ int  sSDb[2][4][64];

  int tid = threadIdx.x;
  int lane = tid & 63, wave = tid >> 6;
  int l15 = lane & 15, quad = lane >> 4;

  ushort_t* mh = (ushort_t*)smem[wave];
  ushort_t* ml = mh + 32*PK2;
  float*    m2 = (float*)smem[wave];

  s16x8 w2h[2][4], w2l[2][4];
  #pragma unroll
  for (int kb = 0; kb < 2; kb++)
    #pragma unroll
    for (int ct = 0; ct < 4; ct++) {
      int off = (ct*16 + l15)*PK2 + kb*32 + quad*8;
      w2h[kb][ct] = *(const s16x8*)(W2hi + off);
      w2l[kb][ct] = *(const s16x8*)(W2lo + off);
    }
  float b1v = b1[lane];
  float b2v[4];
  #pragma unroll
  for (int ct = 0; ct < 4; ct++) b2v[ct] = b2[ct*16 + l15];

  const int* tb = (lane < 32) ? psrc : pdst;
  int lidx = lane & 31;
  int step = gridDim.x * 128;
  int base0 = blockIdx.x * 128;

  // prologue: tile-0 indices + its group-0 gathers
  int sidx = tb[base0 + wave*32 + lidx];
  sSDb[0][wave][lane] = sidx;

  float pv[2][8], qv[2][8];
  #pragma unroll
  for (int i = 0; i < 8; i++) {
    int s = sSDb[0][wave][i];
    int d = sSDb[0][wave][32 + i];
    qv[0][i] = Qbuf[((size_t)s << 6) + lane];
    pv[0][i] = Pbuf[((size_t)d << 6) + lane];
  }

  int cb = 0;
  for (int base = base0; base < NEDGES; base += step) {
    const int* sc = sSDb[cb][wave];
    int nb = base + step;
    int havenext = nb < NEDGES;
    if (havenext) sidx = tb[nb + wave*32 + lidx];   // index prefetch (returns well before use)

    // intra-tile pipelined gather: pack rb from buf[rb&1], gather rb+1 into other
    #pragma unroll
    for (int rb = 0; rb < 4; rb++) {
      int cur = rb & 1;
      if (rb < 3) {
        #pragma unroll
        for (int i = 0; i < 8; i++) {
          int r = (rb+1)*8 + i;
          qv[cur^1][i] = Qbuf[((size_t)sc[r] << 6) + lane];
          pv[cur^1][i] = Pbuf[((size_t)sc[32 + r] << 6) + lane];
        }
      }
      #pragma unroll
      for (int i = 0; i < 8; i += 2) {
        int r = rb*8 + i;
        float v0 = fmaxf(pv[cur][i]   + qv[cur][i]   + b1v, 0.f);
        float v1 = fmaxf(pv[cur][i+1] + qv[cur][i+1] + b1v, 0.f);
        unsigned int ph, pl;
        pack2(v0, v1, ph, pl);
        mh[r*PK2 + lane]     = (ushort_t)(ph & 0xffffu);
        mh[(r+1)*PK2 + lane] = (ushort_t)(ph >> 16);
        ml[r*PK2 + lane]     = (ushort_t)(pl & 0xffffu);
        ml[(r+1)*PK2 + lane] = (ushort_t)(pl >> 16);
      }
    }

    f32x4 facc[2][4];
    #pragma unroll
    for (int rt = 0; rt < 2; rt++)
      #pragma unroll
      for (int ct = 0; ct < 4; ct++)
        facc[rt][ct] = (f32x4){0.f, 0.f, 0.f, 0.f};

    #pragma unroll
    for (int kb = 0; kb < 2; kb++) {
      s16x8 mhf[2], mlf[2];
      #pragma unroll
      for (int rt = 0; rt < 2; rt++) {
        int idx = (rt*16 + l15)*PK2 + kb*32 + quad*8;
        mhf[rt] = *(const s16x8*)&mh[idx];
        mlf[rt] = *(const s16x8*)&ml[idx];
      }
      #pragma unroll
      for (int ct = 0; ct < 4; ct++)
        #pragma unroll
        for (int rt = 0; rt < 2; rt++) {
          // bf16x3: drop ml*w2l
          facc[rt][ct] = __builtin_amdgcn_mfma_f32_16x16x32_bf16(mlf[rt], w2h[kb][ct], facc[rt][ct], 0, 0, 0);
          facc[rt][ct] = __builtin_amdgcn_mfma_f32_16x16x32_bf16(mhf[rt], w2l[kb][ct], facc[rt][ct], 0, 0, 0);
          facc[rt][ct] = __builtin_amdgcn_mfma_f32_16x16x32_bf16(mhf[rt], w2h[kb][ct], facc[rt][ct], 0, 0, 0);
        }
    }

    // cross-tile prefetch: stage next tile's indices + issue its group-0
    // gathers NOW so they are in flight during m2-write + reduce + atomics.
    if (havenext) {
      int* sn = sSDb[cb ^ 1][wave];
      sn[lane] = sidx;
      #pragma unroll
      for (int i = 0; i < 8; i++) {
        qv[0][i] = Qbuf[((size_t)sn[i] << 6) + lane];
        pv[0][i] = Pbuf[((size_t)sn[32 + i] << 6) + lane];
      }
    }

    #pragma unroll
    for (int rt = 0; rt < 2; rt++)
      #pragma unroll
      for (int ct = 0; ct < 4; ct++)
        #pragma unroll
        for (int r = 0; r < 4; r++)
          m2[(rt*16 + quad*4 + r)*68 + ct*16 + l15] = fmaxf(facc[rt][ct][r] + b2v[ct], 0.f);

    // serial 32-row segment reduce (measured-good form)
    int curd = sc[32];
    float acc = 0.f;
    #pragma unroll
    for (int r = 0; r < 32; r++) {
      int d = sc[32 + r];
      float v = m2[r*68 + lane];
      if (d != curd) {
        unsafeAtomicAdd(&agg[((size_t)curd << 6) + lane], acc);
        acc = 0.f; curd = d;
      }
      acc += v;
    }
    unsafeAtomicAdd(&agg[((size_t)curd << 6) + lane], acc);

    cb ^= 1;
  }
}

// ------------- node MLP -------------
__global__ __launch_bounds__(256) void node_mfma_kernel(
    const float* __restrict__ aggF, const float* __restrict__ Rbuf,
    const ushort_t* __restrict__ W1h, const ushort_t* __restrict__ W1l,
    const float* __restrict__ b1,
    const ushort_t* __restrict__ W2h, const ushort_t* __restrict__ W2l,
    const float* __restrict__ b2,
    float* __restrict__ uout, float* __restrict__ sA, float* __restrict__ sB)
{
  __shared__ __align__(16) ushort_t sMh[4][16*PK2];
  __shared__ __align__(16) ushort_t sMl[4][16*PK2];
  int tid = threadIdx.x, lane = tid & 63, wave = tid >> 6;
  int l15 = lane & 15, quad = lane >> 4;
  int base = blockIdx.x * 64 + wave * 16;
  int g = blockIdx.x >> 5;

  s16x8 ah[2], al[2];
  {
    int em = base + l15;
    #pragma unroll
    for (int kb = 0; kb < 2; kb++) {
      size_t off = (size_t)em*64 + kb*32 + quad*8;
      float4 v0 = *(const float4*)(aggF + off);
      float4 v1 = *(const float4*)(aggF + off + 4);
      float vv[8] = {v0.x,v0.y,v0.z,v0.w,v1.x,v1.y,v1.z,v1.w};
      s16x8 hh, ll;
      #pragma unroll
      for (int j = 0; j < 8; j += 2) {
        unsigned int ph, pl;
        pack2(vv[j], vv[j+1], ph, pl);
        hh[j]   = (short)(ph & 0xffffu);
        hh[j+1] = (short)(ph >> 16);
        ll[j]   = (short)(pl & 0xffffu);
        ll[j+1] = (short)(pl >> 16);
      }
      ah[kb] = hh; al[kb] = ll;
    }
  }

  ushort_t* mh = sMh[wave];
  ushort_t* ml = sMl[wave];
  float b1v[4], b2v[4];
  #pragma unroll
  for (int ct = 0; ct < 4; ct++) { b1v[ct] = b1[ct*16+l15]; b2v[ct] = b2[ct*16+l15]; }

  #pragma unroll
  for (int ct = 0; ct < 4; ct++) {
    f32x4 acc = (f32x4){0.f, 0.f, 0.f, 0.f};
    #pragma unroll
    for (int kb = 0; kb < 2; kb++) {
      int woff = (ct*16 + l15)*PK2 + kb*32 + quad*8;
      s16x8 bh = *(const s16x8*)(W1h + woff);
      s16x8 bl = *(const s16x8*)(W1l + woff);
      // bf16x3: drop al*bl
      acc = __builtin_amdgcn_mfma_f32_16x16x32_bf16(al[kb], bh, acc, 0, 0, 0);
      acc = __builtin_amdgcn_mfma_f32_16x16x32_bf16(ah[kb], bl, acc, 0, 0, 0);
      acc = __builtin_amdgcn_mfma_f32_16x16x32_bf16(ah[kb], bh, acc, 0, 0, 0);
    }
    int j = ct*16 + l15;
    #pragma unroll
    for (int rr = 0; rr < 4; rr += 2) {
      int row = quad*4 + rr;
      float v0 = fmaxf(acc[rr]   + Rbuf[(size_t)(base+row)*64   + j] + b1v[ct], 0.f);
      float v1 = fmaxf(acc[rr+1] + Rbuf[(size_t)(base+row+1)*64 + j] + b1v[ct], 0.f);
      unsigned int ph, pl;
      pack2(v0, v1, ph, pl);
      mh[row*PK2 + j]     = (ushort_t)(ph & 0xffffu);
      mh[(row+1)*PK2 + j] = (ushort_t)(ph >> 16);
      ml[row*PK2 + j]     = (ushort_t)(pl & 0xffffu);
      ml[(row+1)*PK2 + j] = (ushort_t)(pl >> 16);
    }
  }

  s16x8 mhf[2], mlf[2];
  #pragma unroll
  for (int kb = 0; kb < 2; kb++) {
    int idx = l15*PK2 + kb*32 + quad*8;
    mhf[kb] = *(const s16x8*)&mh[idx];
    mlf[kb] = *(const s16x8*)&ml[idx];
  }
  #pragma unroll
  for (int ct = 0; ct < 4; ct++) {
    f32x4 facc = (f32x4){0.f, 0.f, 0.f, 0.f};
    #pragma unroll
    for (int kb = 0; kb < 2; kb++) {
      int woff = (ct*16 + l15)*PK2 + kb*32 + quad*8;
      s16x8 bh = *(const s16x8*)(W2h + woff);
      s16x8 bl = *(const s16x8*)(W2l + woff);
      // bf16x3: drop mlf*bl
      facc = __builtin_amdgcn_mfma_f32_16x16x32_bf16(mlf[kb], bh, facc, 0, 0, 0);
      facc = __builtin_amdgcn_mfma_f32_16x16x32_bf16(mhf[kb], bl, facc, 0, 0, 0);
      facc = __builtin_amdgcn_mfma_f32_16x16x32_bf16(mhf[kb], bh, facc, 0, 0, 0);
    }
    int j = ct*16 + l15;
    float s = 0.f, s2 = 0.f;
    #pragma unroll
    for (int rr = 0; rr < 4; rr++) {
      int row = quad*4 + rr;
      float v = fmaxf(facc[rr] + b2v[ct], 0.f);
      uout[(size_t)(base+row)*64 + j] = v;
      s += v; s2 += v*v;
    }
    s  += __shfl_xor(s, 16);  s  += __shfl_xor(s, 32);
    s2 += __shfl_xor(s2, 16); s2 += __shfl_xor(s2, 32);
    if (quad == 0) {
      unsafeAtomicAdd(&sA[g*64 + j], s);
      unsafeAtomicAdd(&sB[g*64 + j], s2);
    }
  }
}

// ------------- decoder -------------
__global__ __launch_bounds__(64) void decoder_kernel(
    const float* __restrict__ u, const float* __restrict__ sA,
    const float* __restrict__ sB, const float* __restrict__ W,
    const float* __restrict__ b, float* __restrict__ X)
{
  __shared__ float sh[64][65];
  __shared__ float sm[64], sr[64];
  int lane = threadIdx.x;
  int nb = blockIdx.x * 64;
  int g = blockIdx.x >> 5;
  {
    float a = sA[g*64 + lane], q = sB[g*64 + lane];
    float mean = a * (1.f / NSAMP);
    float var = q * (1.f / NSAMP) - mean * mean;
    sm[lane] = mean;
    sr[lane] = rsqrtf(var + EPS);
  }
  for (int r = 0; r < 64; r++) sh[r][lane] = u[(size_t)(nb + r) * 64 + lane];
  __syncthreads();
  float a0 = b[0], a1 = b[1], a2 = b[2];
  #pragma unroll
  for (int c = 0; c < 64; c++) {
    float v = (sh[lane][c] - sm[c]) * sr[c];
    a0 = fmaf(v, W[c*3+0], a0);
    a1 = fmaf(v, W[c*3+1], a1);
    a2 = fmaf(v, W[c*3+2], a2);
  }
  float inv = 1.f / sqrtf(a0*a0 + a1*a1 + a2*a2);
  int n = nb + lane;
  X[n*3+0] = a0 * inv;
  X[n*3+1] = a1 * inv;
  X[n*3+2] = a2 * inv;
}

// ------------- MMD: R16 register-blocked kXX (8 m-points/thread) ----------
// kXX: 512 blocks = 16 graphs x 32 n-tiles; thread holds 8 m-points in regs,
//      loops n=0..63 -> 3 LDS reads serve 8 pairs (8x fewer ds_reads than R13).
// kXY: 64 blocks  = 16 graphs x 4 n-splits (R14 form, atomic into zeroed kxy).
__device__ inline float block_reduce_sum(float v) {
  #pragma unroll
  for (int o = 32; o > 0; o >>= 1) v += __shfl_down(v, o, 64);
  __shared__ float red[4];
  int lane = threadIdx.x & 63, w = threadIdx.x >> 6;
  if (lane == 0) red[w] = v;
  __syncthreads();
  float t = 0.f;
  if (threadIdx.x == 0) t = red[0] + red[1] + red[2] + red[3];
  return t;
}

__global__ __launch_bounds__(256) void mmd_kernel(
    const float* __restrict__ X, YArr Y,
    float* __restrict__ kxx, float* __restrict__ kxy)
{
  if (blockIdx.x < 512) {
    int b  = blockIdx.x >> 5;
    int nt = blockIdx.x & 31;
    const float* Xb = X + (size_t)b * NSAMP * 3;
    __shared__ float sx[192];
    if (threadIdx.x < 192) sx[threadIdx.x] = Xb[nt*192 + threadIdx.x];
    __syncthreads();
    // 8 m-points per thread in registers (stride 256)
    float mx0[8], mx1[8], mx2[8], ac[8];
    #pragma unroll
    for (int k = 0; k < 8; k++) {
      int m = k*256 + threadIdx.x;
      mx0[k] = Xb[m*3+0]; mx1[k] = Xb[m*3+1]; mx2[k] = Xb[m*3+2];
      ac[k] = 0.f;
    }
    for (int n = 0; n < 64; n++) {
      float s0 = sx[n*3+0], s1 = sx[n*3+1], s2 = sx[n*3+2];
      #pragma unroll
      for (int k = 0; k < 8; k++) {
        float d = fmaf(mx2[k], s2, fmaf(mx1[k], s1, mx0[k]*s0));
        ac[k] += __expf(2.f*d - 2.f);
      }
    }
    float ps = ((ac[0]+ac[1])+(ac[2]+ac[3])) + ((ac[4]+ac[5])+(ac[6]+ac[7]));
    float t2 = block_reduce_sum(ps);
    if (threadIdx.x == 0) atomicAdd(&kxx[b], t2);
  } else {
    int t  = blockIdx.x - 512;
    int b  = t >> 2;
    int ms = t & 3;
    const float* Xb = X + (size_t)b * NSAMP * 3;
    float ps = 0.f;
    #pragma unroll
    for (int it = 0; it < 2; it++) {
      int n = ms*512 + it*256 + threadIdx.x;
      float x0 = Xb[n*3+0], x1 = Xb[n*3+1], x2 = Xb[n*3+2];
      #pragma unroll
      for (int m = 0; m < 64; m++) {
        float d = x0*Y.v[m*3+0] + x1*Y.v[m*3+1] + x2*Y.v[m*3+2];
        ps += __expf(2.f*d - 2.f);
      }
    }
    float t2 = block_reduce_sum(ps);
    if (threadIdx.x == 0) atomicAdd(&kxy[b], t2);
  }
}

__global__ void loss_kernel(const float* __restrict__ kxx,
                            const float* __restrict__ kxy,
                            float kyy, float* __restrict__ out)
{
  if (threadIdx.x == 0 && blockIdx.x == 0) {
    float s = 0.f;
    for (int b = 0; b < NBATCH; b++)
      s += kxx[b] * (1.0f/((float)NSAMP*(float)NSAMP))
         - 2.0f * kxy[b] * (1.0f/((float)NSAMP*64.0f));
    out[0] = s * (1.0f/NBATCH) + kyy;
  }
}

// ------------- launch -------------
extern "C" void kernel_launch(void* const* d_in, const int* in_sizes, int n_in,
                              void* d_out, int out_size, void* d_ws, size_t ws_size,
                              hipStream_t stream)
{
  const float* x    = (const float*)d_in[0];
  const int*   esrc = (const int*)  d_in[1];
  const int*   edst = (const int*)  d_in[2];
  const float* encW = (const float*)d_in[4];
  const float* encb = (const float*)d_in[5];
  const float* m1W  = (const float*)d_in[6];
  const float* m1b  = (const float*)d_in[7];
  const float* m2W  = (const float*)d_in[8];
  const float* m2b  = (const float*)d_in[9];
  const float* u1W  = (const float*)d_in[10];
  const float* u1b  = (const float*)d_in[11];
  const float* u2W  = (const float*)d_in[12];
  const float* u2b  = (const float*)d_in[13];
  const float* decW = (const float*)d_in[14];
  const float* decb = (const float*)d_in[15];
  float* out = (float*)d_out;

  const size_t NF = (size_t)NNODES * 64;
  // single zero region: [aggAll | statsA | statsB | kxx | kxy | icnt]
  float* aggAll = (float*)d_ws;        // 4 * NF
  float* statsA = aggAll + 4*NF;       // 4096
  float* statsB = statsA + 4096;       // 4096
  float* kxx    = statsB + 4096;       // 16
  float* kxy    = kxx + 16;            // 16 (zeroed; atomicAdd target)
  int*   icnt   = (int*)(kxy + 16);    // 32768
  size_t zero_bytes = (4*NF + 4096 + 4096 + 32) * sizeof(float) + NNODES * sizeof(int);

  float* u_buf  = (float*)(icnt + NNODES);
  float* Pbuf   = u_buf + NF;
  float* Qbuf   = Pbuf + NF;
  float* Rbuf   = Qbuf + NF;
  int* ioffs    = (int*)(Rbuf + NF + 16);   // +16 pad keeps legacy layout offsets
  int* icur     = ioffs + NNODES;
  int* psrc     = icur + NNODES;
  int* pdst     = psrc + NEDGES;
  ushort_t* us  = (ushort_t*)(pdst + NEDGES);
  ushort_t* wc_hi  = us;  us += 4*192*PK2;
  ushort_t* wc_lo  = us;  us += 4*192*PK2;
  ushort_t* w1b_hi = us;  us += 4*64*PK2;
  ushort_t* w1b_lo = us;  us += 4*64*PK2;
  ushort_t* w2e_hi = us;  us += 4*64*PK2;
  ushort_t* w2e_lo = us;  us += 4*64*PK2;
  ushort_t* w2n_hi = us;  us += 4*64*PK2;
  ushort_t* w2n_lo = us;  us += 4*64*PK2;

  float* X = out + 1;

  hipMemsetAsync(aggAll, 0, zero_bytes, stream);

  setup_kernel<<<384 + NEDGES/256, 256, 0, stream>>>(
      m1W, m2W, u1W, u2W,
      wc_hi, wc_lo, w1b_hi, w1b_lo, w2e_hi, w2e_lo, w2n_hi, w2n_lo,
      edst, icnt);
  scan_kernel<<<1, 1024, 0, stream>>>(icnt, ioffs, icur);
  fill_kernel<<<NEDGES/256, 256, 0, stream>>>(esrc, edst, icur, psrc, pdst);

  for (int l = 0; l < 4; l++) {
    const ushort_t* wch = wc_hi + (size_t)l*192*PK2;
    const ushort_t* wcl = wc_lo + (size_t)l*192*PK2;
    if (l == 0)
      norm_pqr_kernel<0><<<512, 256, 0, stream>>>(
          x, nullptr, nullptr, encW, encb, wch, wcl, Pbuf, Qbuf, Rbuf);
    else
      norm_pqr_kernel<1><<<512, 256, 0, stream>>>(
          u_buf, statsA + (l-1)*1024, statsB + (l-1)*1024, nullptr, nullptr,
          wch, wcl, Pbuf, Qbuf, Rbuf);

    edge_fused_kernel<<<768, 256, 0, stream>>>(
        Pbuf, Qbuf, psrc, pdst, m1b + l*64,
        w2e_hi + (size_t)l*64*PK2, w2e_lo + (size_t)l*64*PK2, m2b + l*64,
        aggAll + (size_t)l*NF);

    node_mfma_kernel<<<512, 256, 0, stream>>>(
        aggAll + (size_t)l*NF, Rbuf,
        w1b_hi + (size_t)l*64*PK2, w1b_lo + (size_t)l*64*PK2, u1b + l*64,
        w2n_hi + (size_t)l*64*PK2, w2n_lo + (size_t)l*64*PK2, u2b + l*64,
        u_buf, statsA + l*1024, statsB + l*1024);
  }

  decoder_kernel<<<NNODES/64, 64, 0, stream>>>(
      u_buf, statsA + 3*1024, statsB + 3*1024, decW, decb, X);

  YArr Y;
  {
    const double pi = 3.14159265358979323846;
    double phi = pi * (3.0 - sqrt(5.0));
    for (int i = 0; i < 64; i++) {
      double y  = 1.0 - 2.0 * (double)i / 63.0;
      double r  = sqrt(fmax(0.0, 1.0 - y*y));
      double th = phi * (double)i;
      Y.v[i*3+0] = (float)(cos(th) * r);
      Y.v[i*3+1] = (float)y;
      Y.v[i*3+2] = (float)(sin(th) * r);
    }
  }
  double kyy_acc = 0.0;
  for (int i = 0; i < 64; i++)
    for (int j = 0; j < 64; j++) {
      double d = (double)Y.v[i*3+0]*Y.v[j*3+0]
               + (double)Y.v[i*3+1]*Y.v[j*3+1]
               + (double)Y.v[i*3+2]*Y.v[j*3+2];
      kyy_acc += exp(2.0*d - 2.0);
    }
  float kyy = (float)(kyy_acc / 4096.0);

  mmd_kernel<<<512 + 64, 256, 0, stream>>>(X, Y, kxx, kxy);
  loss_kernel<<<1, 64, 0, stream>>>(kxx, kxy, kyy, out);
}

// Round 18
// 408.249 us; speedup vs baseline: 1.0511x; 1.0188x over previous
//
#include <hip/hip_runtime.h>
#include <cmath>

#define NNODES 32768
#define NEDGES 524288
#define NBATCH 16
#define NSAMP  2048
#define EPS    1e-5f

#define PK2 72    // 64 + 8 pad (shorts); row stride 144 B (16B-multiple)

typedef short s16x8 __attribute__((ext_vector_type(8)));
typedef float f32x4 __attribute__((ext_vector_type(4)));
typedef unsigned int u32x4 __attribute__((ext_vector_type(4)));
typedef unsigned short ushort_t;

struct YArr { float v[192]; };

static __device__ __forceinline__ unsigned short f2bf(float f) {
  unsigned int u = __float_as_uint(f);
  u = (u + 0x7fffu + ((u >> 16) & 1u)) >> 16;   // RN-even
  return (unsigned short)u;
}
static __device__ __forceinline__ float bf2f(unsigned short b) {
  return __uint_as_float(((unsigned int)b) << 16);
}

// pack two f32 into bf16 hi-pair + residual lo-pair via HW cvt_pk (1 instr per pair)
// ph = [bf16(v1) | bf16(v0)], pl = [bf16(v1-h1) | bf16(v0-h0)]
static __device__ __forceinline__ void pack2(float v0, float v1,
                                             unsigned int& ph, unsigned int& pl) {
  asm("v_cvt_pk_bf16_f32 %0, %1, %2" : "=v"(ph) : "v"(v0), "v"(v1));
  float h0 = __uint_as_float(ph << 16);
  float h1 = __uint_as_float(ph & 0xffff0000u);
  asm("v_cvt_pk_bf16_f32 %0, %1, %2" : "=v"(pl) : "v"(v0 - h0), "v"(v1 - h1));
}

// ------------- setup: weight prep (blocks 0..383) + CSR count (blocks 384..) ----
__global__ __launch_bounds__(256) void setup_kernel(
    const float* __restrict__ m1W, const float* __restrict__ m2W,
    const float* __restrict__ u1W, const float* __restrict__ u2W,
    ushort_t* __restrict__ wc_hi, ushort_t* __restrict__ wc_lo,
    ushort_t* __restrict__ w1b_hi, ushort_t* __restrict__ w1b_lo,
    ushort_t* __restrict__ w2e_hi, ushort_t* __restrict__ w2e_lo,
    ushort_t* __restrict__ w2n_hi, ushort_t* __restrict__ w2n_lo,
    const int* __restrict__ edst, int* __restrict__ cnt)
{
  if (blockIdx.x >= 384) {
    int e = (blockIdx.x - 384) * 256 + threadIdx.x;
    if (e < NEDGES) atomicAdd(&cnt[edst[e]], 1);
    return;
  }
  int t = blockIdx.x * 256 + threadIdx.x;
  if (t >= 4 * 24576) return;
  int l = t / 24576;
  int r = t % 24576;
  float w; ushort_t *dh, *dl;
  if (r < 12288) {                      // Wcomb: P|Q|R
    int j = r >> 6, k = r & 63;
    if (j < 64)       w = m1W[l*8192 + k*64 + j];
    else if (j < 128) w = m1W[l*8192 + (64 + k)*64 + (j - 64)];
    else              w = u1W[l*8192 + k*64 + (j - 128)];
    int off = l*192*PK2 + j*PK2 + k;
    dh = wc_hi + off; dl = wc_lo + off;
  } else if (r < 16384) {               // W1b
    int idx = r - 12288;
    int j = idx & 63, k = idx >> 6;
    w = u1W[l*8192 + (64 + k)*64 + j];
    int off = l*64*PK2 + j*PK2 + k;
    dh = w1b_hi + off; dl = w1b_lo + off;
  } else if (r < 20480) {               // W2e
    int idx = r - 16384;
    int j = idx & 63, k = idx >> 6;
    w = m2W[l*4096 + k*64 + j];
    int off = l*64*PK2 + j*PK2 + k;
    dh = w2e_hi + off; dl = w2e_lo + off;
  } else {                              // W2n
    int idx = r - 20480;
    int j = idx & 63, k = idx >> 6;
    w = u2W[l*4096 + k*64 + j];
    int off = l*64*PK2 + j*PK2 + k;
    dh = w2n_hi + off; dl = w2n_lo + off;
  }
  unsigned short hb = f2bf(w);
  *dh = hb;
  *dl = f2bf(w - bf2f(hb));
}

__global__ __launch_bounds__(1024) void scan_kernel(const int* __restrict__ cnt,
                                                    int* __restrict__ offs,
                                                    int* __restrict__ cursor) {
  __shared__ int sc[1024];
  int tid = threadIdx.x;
  int base = tid * 32;
  int s = 0;
  #pragma unroll
  for (int i = 0; i < 32; i++) s += cnt[base + i];
  sc[tid] = s; __syncthreads();
  int own = s;
  for (int off = 1; off < 1024; off <<= 1) {
    int v = (tid >= off) ? sc[tid - off] : 0;
    __syncthreads();
    sc[tid] += v;
    __syncthreads();
  }
  int run = sc[tid] - own;
  for (int i = 0; i < 32; i++) {
    offs[base + i] = run; cursor[base + i] = run;
    run += cnt[base + i];
  }
}

__global__ __launch_bounds__(256) void fill_kernel(
    const int* __restrict__ esrc, const int* __restrict__ edst,
    int* __restrict__ cursor, int* __restrict__ psrc, int* __restrict__ pdst) {
  int e = blockIdx.x * 256 + threadIdx.x;
  if (e < NEDGES) {
    int d = edst[e];
    int pos = atomicAdd(&cursor[d], 1);
    psrc[pos] = esrc[e];
    pdst[pos] = d;
  }
}

// ------------- fused (encode|norm) + P|Q|R GEMM -------------
// R17: m1 bias folded into P output (b1e) so edge kernel needs no b1.
template<int MODE>
__global__ __launch_bounds__(256) void norm_pqr_kernel(
    const float* __restrict__ in,     // x (MODE 0) or u (MODE 1)
    const float* __restrict__ sA, const float* __restrict__ sB,
    const float* __restrict__ encW, const float* __restrict__ encb,
    const ushort_t* __restrict__ Wh, const ushort_t* __restrict__ Wl,
    const float* __restrict__ b1e,
    float* __restrict__ P, float* __restrict__ Q, float* __restrict__ Rb)
{
  __shared__ __align__(16) ushort_t sAh[4][16*PK2];
  __shared__ __align__(16) ushort_t sAl[4][16*PK2];
  int tid = threadIdx.x, lane = tid & 63, wave = tid >> 6;
  int l15 = lane & 15, quad = lane >> 4;
  int base = blockIdx.x * 64 + wave * 16;
  int g = blockIdx.x >> 5;

  float mean = 0.f, rstd = 1.f, w0 = 0.f, w1 = 0.f, w2 = 0.f, bb = 0.f;
  if (MODE) {
    float a = sA[g*64 + lane], q = sB[g*64 + lane];
    mean = a * (1.f / NSAMP);
    float var = q * (1.f / NSAMP) - mean * mean;
    rstd = rsqrtf(var + EPS);
  } else {
    w0 = encW[lane]; w1 = encW[64 + lane]; w2 = encW[128 + lane];
    bb = encb[lane];
  }

  ushort_t* ah_s = sAh[wave];
  ushort_t* al_s = sAl[wave];
  #pragma unroll
  for (int r = 0; r < 16; r += 2) {
    int n = base + r;
    float v0, v1;
    if (MODE) {
      v0 = (in[(size_t)n*64 + lane] - mean) * rstd;
      v1 = (in[(size_t)(n+1)*64 + lane] - mean) * rstd;
    } else {
      v0 = fmaf(in[n*3+2], w2, fmaf(in[n*3+1], w1, fmaf(in[n*3+0], w0, bb)));
      v1 = fmaf(in[(n+1)*3+2], w2, fmaf(in[(n+1)*3+1], w1, fmaf(in[(n+1)*3+0], w0, bb)));
    }
    unsigned int ph, pl;
    pack2(v0, v1, ph, pl);
    ah_s[r*PK2 + lane]     = (ushort_t)(ph & 0xffffu);
    ah_s[(r+1)*PK2 + lane] = (ushort_t)(ph >> 16);
    al_s[r*PK2 + lane]     = (ushort_t)(pl & 0xffffu);
    al_s[(r+1)*PK2 + lane] = (ushort_t)(pl >> 16);
  }

  s16x8 ah[2], al[2];
  #pragma unroll
  for (int kb = 0; kb < 2; kb++) {
    int idx = l15*PK2 + kb*32 + quad*8;
    ah[kb] = *(const s16x8*)&ah_s[idx];
    al[kb] = *(const s16x8*)&al_s[idx];
  }

  #pragma unroll
  for (int ct = 0; ct < 12; ct++) {
    f32x4 acc = (f32x4){0.f, 0.f, 0.f, 0.f};
    #pragma unroll
    for (int kb = 0; kb < 2; kb++) {
      int woff = (ct*16 + l15)*PK2 + kb*32 + quad*8;
      s16x8 bh = *(const s16x8*)(Wh + woff);
      s16x8 bl = *(const s16x8*)(Wl + woff);
      // bf16x3: drop al*bl (≤2^-18 relative ≈ 4e-6 per term)
      acc = __builtin_amdgcn_mfma_f32_16x16x32_bf16(al[kb], bh, acc, 0, 0, 0);
      acc = __builtin_amdgcn_mfma_f32_16x16x32_bf16(ah[kb], bl, acc, 0, 0, 0);
      acc = __builtin_amdgcn_mfma_f32_16x16x32_bf16(ah[kb], bh, acc, 0, 0, 0);
    }
    int j = ct*16 + l15;
    float* dst; int jj; float addv = 0.f;
    if (ct < 4)      { dst = P;  jj = j; addv = b1e[jj]; }
    else if (ct < 8) { dst = Q;  jj = j - 64; }
    else             { dst = Rb; jj = j - 128; }
    #pragma unroll
    for (int rr = 0; rr < 4; rr++) {
      int row = base + quad*4 + rr;
      dst[(size_t)row*64 + jj] = acc[rr] + addv;
    }
  }
}

// ------------- fused edge MLP + segment-reduce (grid 768) --------
// R17: direct-fragment gather — each lane loads its MFMA fragment rows
// straight from P/Q (float4 x2 per row), packs hi/lo in-register via cvt_pk.
// No staging LDS at all (removes 64 ds_write_b16 + 8 ds_read_b128 per
// lane-tile). b1 pre-folded into P by norm_pqr. m2 transpose + serial
// reduce + atomics unchanged (measured-good).
__global__ __launch_bounds__(256, 3) void edge_fused_kernel(
    const float* __restrict__ Pbuf, const float* __restrict__ Qbuf,
    const int* __restrict__ psrc, const int* __restrict__ pdst,
    const ushort_t* __restrict__ W2hi, const ushort_t* __restrict__ W2lo,
    const float* __restrict__ b2,
    float* __restrict__ agg)
{
  __shared__ __align__(16) float m2s[4][32*68];
  __shared__ int sSDb[2][4][64];

  int tid = threadIdx.x;
  int lane = tid & 63, wave = tid >> 6;
  int l15 = lane & 15, quad = lane >> 4;

  float* m2 = m2s[wave];

  s16x8 w2h[2][4], w2l[2][4];
  #pragma unroll
  for (int kb = 0; kb < 2; kb++)
    #pragma unroll
    for (int ct = 0; ct < 4; ct++) {
      int off = (ct*16 + l15)*PK2 + kb*32 + quad*8;
      w2h[kb][ct] = *(const s16x8*)(W2hi + off);
      w2l[kb][ct] = *(const s16x8*)(W2lo + off);
    }
  float b2v[4];
  #pragma unroll
  for (int ct = 0; ct < 4; ct++) b2v[ct] = b2[ct*16 + l15];

  const int* tb = (lane < 32) ? psrc : pdst;
  int lidx = lane & 31;
  int step = gridDim.x * 128;
  int base0 = blockIdx.x * 128;

  int sidx = tb[base0 + wave*32 + lidx];
  sSDb[0][wave][lane] = sidx;

  int cb = 0;
  for (int base = base0; base < NEDGES; base += step) {
    const int* sc = sSDb[cb][wave];
    int nb = base + step;
    int havenext = nb < NEDGES;
    if (havenext) sidx = tb[nb + wave*32 + lidx];   // index prefetch

    // direct fragment gather + in-register hi/lo pack
    s16x8 pah[2][2], pal[2][2];     // [kb][rt]
    #pragma unroll
    for (int kb = 0; kb < 2; kb++) {
      float4 qq[2][2], pp[2][2];    // [rt][half] — 8 loads in flight per kb
      #pragma unroll
      for (int rt = 0; rt < 2; rt++) {
        int srow = sc[rt*16 + l15];
        int drow = sc[32 + rt*16 + l15];
        const float* qp = Qbuf + (((size_t)srow) << 6) + kb*32 + quad*8;
        const float* pd = Pbuf + (((size_t)drow) << 6) + kb*32 + quad*8;
        qq[rt][0] = *(const float4*)(qp);
        qq[rt][1] = *(const float4*)(qp + 4);
        pp[rt][0] = *(const float4*)(pd);
        pp[rt][1] = *(const float4*)(pd + 4);
      }
      #pragma unroll
      for (int rt = 0; rt < 2; rt++) {
        float v0 = fmaxf(pp[rt][0].x + qq[rt][0].x, 0.f);
        float v1 = fmaxf(pp[rt][0].y + qq[rt][0].y, 0.f);
        float v2 = fmaxf(pp[rt][0].z + qq[rt][0].z, 0.f);
        float v3 = fmaxf(pp[rt][0].w + qq[rt][0].w, 0.f);
        float v4 = fmaxf(pp[rt][1].x + qq[rt][1].x, 0.f);
        float v5 = fmaxf(pp[rt][1].y + qq[rt][1].y, 0.f);
        float v6 = fmaxf(pp[rt][1].z + qq[rt][1].z, 0.f);
        float v7 = fmaxf(pp[rt][1].w + qq[rt][1].w, 0.f);
        unsigned int h0,h1,h2,h3,l0,l1,l2,l3;
        pack2(v0, v1, h0, l0);
        pack2(v2, v3, h1, l1);
        pack2(v4, v5, h2, l2);
        pack2(v6, v7, h3, l3);
        u32x4 uh = (u32x4){h0, h1, h2, h3};
        u32x4 ul = (u32x4){l0, l1, l2, l3};
        pah[kb][rt] = __builtin_bit_cast(s16x8, uh);
        pal[kb][rt] = __builtin_bit_cast(s16x8, ul);
      }
    }

    f32x4 facc[2][4];
    #pragma unroll
    for (int rt = 0; rt < 2; rt++)
      #pragma unroll
      for (int ct = 0; ct < 4; ct++)
        facc[rt][ct] = (f32x4){0.f, 0.f, 0.f, 0.f};

    #pragma unroll
    for (int kb = 0; kb < 2; kb++)
      #pragma unroll
      for (int ct = 0; ct < 4; ct++)
        #pragma unroll
        for (int rt = 0; rt < 2; rt++) {
          // bf16x3: drop pal*w2l
          facc[rt][ct] = __builtin_amdgcn_mfma_f32_16x16x32_bf16(pal[kb][rt], w2h[kb][ct], facc[rt][ct], 0, 0, 0);
          facc[rt][ct] = __builtin_amdgcn_mfma_f32_16x16x32_bf16(pah[kb][rt], w2l[kb][ct], facc[rt][ct], 0, 0, 0);
          facc[rt][ct] = __builtin_amdgcn_mfma_f32_16x16x32_bf16(pah[kb][rt], w2h[kb][ct], facc[rt][ct], 0, 0, 0);
        }

    // stage next tile's indices during m2-write + reduce + atomics
    if (havenext) sSDb[cb ^ 1][wave][lane] = sidx;

    #pragma unroll
    for (int rt = 0; rt < 2; rt++)
      #pragma unroll
      for (int ct = 0; ct < 4; ct++)
        #pragma unroll
        for (int r = 0; r < 4; r++)
          m2[(rt*16 + quad*4 + r)*68 + ct*16 + l15] = fmaxf(facc[rt][ct][r] + b2v[ct], 0.f);

    // serial 32-row segment reduce (measured-good form)
    int curd = sc[32];
    float acc = 0.f;
    #pragma unroll
    for (int r = 0; r < 32; r++) {
      int d = sc[32 + r];
      float v = m2[r*68 + lane];
      if (d != curd) {
        unsafeAtomicAdd(&agg[((size_t)curd << 6) + lane], acc);
        acc = 0.f; curd = d;
      }
      acc += v;
    }
    unsafeAtomicAdd(&agg[((size_t)curd << 6) + lane], acc);

    cb ^= 1;
  }
}

// ------------- node MLP -------------
__global__ __launch_bounds__(256) void node_mfma_kernel(
    const float* __restrict__ aggF, const float* __restrict__ Rbuf,
    const ushort_t* __restrict__ W1h, const ushort_t* __restrict__ W1l,
    const float* __restrict__ b1,
    const ushort_t* __restrict__ W2h, const ushort_t* __restrict__ W2l,
    const float* __restrict__ b2,
    float* __restrict__ uout, float* __restrict__ sA, float* __restrict__ sB)
{
  __shared__ __align__(16) ushort_t sMh[4][16*PK2];
  __shared__ __align__(16) ushort_t sMl[4][16*PK2];
  int tid = threadIdx.x, lane = tid & 63, wave = tid >> 6;
  int l15 = lane & 15, quad = lane >> 4;
  int base = blockIdx.x * 64 + wave * 16;
  int g = blockIdx.x >> 5;

  s16x8 ah[2], al[2];
  {
    int em = base + l15;
    #pragma unroll
    for (int kb = 0; kb < 2; kb++) {
      size_t off = (size_t)em*64 + kb*32 + quad*8;
      float4 v0 = *(const float4*)(aggF + off);
      float4 v1 = *(const float4*)(aggF + off + 4);
      float vv[8] = {v0.x,v0.y,v0.z,v0.w,v1.x,v1.y,v1.z,v1.w};
      s16x8 hh, ll;
      #pragma unroll
      for (int j = 0; j < 8; j += 2) {
        unsigned int ph, pl;
        pack2(vv[j], vv[j+1], ph, pl);
        hh[j]   = (short)(ph & 0xffffu);
        hh[j+1] = (short)(ph >> 16);
        ll[j]   = (short)(pl & 0xffffu);
        ll[j+1] = (short)(pl >> 16);
      }
      ah[kb] = hh; al[kb] = ll;
    }
  }

  ushort_t* mh = sMh[wave];
  ushort_t* ml = sMl[wave];
  float b1v[4], b2v[4];
  #pragma unroll
  for (int ct = 0; ct < 4; ct++) { b1v[ct] = b1[ct*16+l15]; b2v[ct] = b2[ct*16+l15]; }

  #pragma unroll
  for (int ct = 0; ct < 4; ct++) {
    f32x4 acc = (f32x4){0.f, 0.f, 0.f, 0.f};
    #pragma unroll
    for (int kb = 0; kb < 2; kb++) {
      int woff = (ct*16 + l15)*PK2 + kb*32 + quad*8;
      s16x8 bh = *(const s16x8*)(W1h + woff);
      s16x8 bl = *(const s16x8*)(W1l + woff);
      // bf16x3: drop al*bl
      acc = __builtin_amdgcn_mfma_f32_16x16x32_bf16(al[kb], bh, acc, 0, 0, 0);
      acc = __builtin_amdgcn_mfma_f32_16x16x32_bf16(ah[kb], bl, acc, 0, 0, 0);
      acc = __builtin_amdgcn_mfma_f32_16x16x32_bf16(ah[kb], bh, acc, 0, 0, 0);
    }
    int j = ct*16 + l15;
    #pragma unroll
    for (int rr = 0; rr < 4; rr += 2) {
      int row = quad*4 + rr;
      float v0 = fmaxf(acc[rr]   + Rbuf[(size_t)(base+row)*64   + j] + b1v[ct], 0.f);
      float v1 = fmaxf(acc[rr+1] + Rbuf[(size_t)(base+row+1)*64 + j] + b1v[ct], 0.f);
      unsigned int ph, pl;
      pack2(v0, v1, ph, pl);
      mh[row*PK2 + j]     = (ushort_t)(ph & 0xffffu);
      mh[(row+1)*PK2 + j] = (ushort_t)(ph >> 16);
      ml[row*PK2 + j]     = (ushort_t)(pl & 0xffffu);
      ml[(row+1)*PK2 + j] = (ushort_t)(pl >> 16);
    }
  }

  s16x8 mhf[2], mlf[2];
  #pragma unroll
  for (int kb = 0; kb < 2; kb++) {
    int idx = l15*PK2 + kb*32 + quad*8;
    mhf[kb] = *(const s16x8*)&mh[idx];
    mlf[kb] = *(const s16x8*)&ml[idx];
  }
  #pragma unroll
  for (int ct = 0; ct < 4; ct++) {
    f32x4 facc = (f32x4){0.f, 0.f, 0.f, 0.f};
    #pragma unroll
    for (int kb = 0; kb < 2; kb++) {
      int woff = (ct*16 + l15)*PK2 + kb*32 + quad*8;
      s16x8 bh = *(const s16x8*)(W2h + woff);
      s16x8 bl = *(const s16x8*)(W2l + woff);
      // bf16x3: drop mlf*bl
      facc = __builtin_amdgcn_mfma_f32_16x16x32_bf16(mlf[kb], bh, facc, 0, 0, 0);
      facc = __builtin_amdgcn_mfma_f32_16x16x32_bf16(mhf[kb], bl, facc, 0, 0, 0);
      facc = __builtin_amdgcn_mfma_f32_16x16x32_bf16(mhf[kb], bh, facc, 0, 0, 0);
    }
    int j = ct*16 + l15;
    float s = 0.f, s2 = 0.f;
    #pragma unroll
    for (int rr = 0; rr < 4; rr++) {
      int row = quad*4 + rr;
      float v = fmaxf(facc[rr] + b2v[ct], 0.f);
      uout[(size_t)(base+row)*64 + j] = v;
      s += v; s2 += v*v;
    }
    s  += __shfl_xor(s, 16);  s  += __shfl_xor(s, 32);
    s2 += __shfl_xor(s2, 16); s2 += __shfl_xor(s2, 32);
    if (quad == 0) {
      unsafeAtomicAdd(&sA[g*64 + j], s);
      unsafeAtomicAdd(&sB[g*64 + j], s2);
    }
  }
}

// ------------- decoder -------------
__global__ __launch_bounds__(64) void decoder_kernel(
    const float* __restrict__ u, const float* __restrict__ sA,
    const float* __restrict__ sB, const float* __restrict__ W,
    const float* __restrict__ b, float* __restrict__ X)
{
  __shared__ float sh[64][65];
  __shared__ float sm[64], sr[64];
  int lane = threadIdx.x;
  int nb = blockIdx.x * 64;
  int g = blockIdx.x >> 5;
  {
    float a = sA[g*64 + lane], q = sB[g*64 + lane];
    float mean = a * (1.f / NSAMP);
    float var = q * (1.f / NSAMP) - mean * mean;
    sm[lane] = mean;
    sr[lane] = rsqrtf(var + EPS);
  }
  for (int r = 0; r < 64; r++) sh[r][lane] = u[(size_t)(nb + r) * 64 + lane];
  __syncthreads();
  float a0 = b[0], a1 = b[1], a2 = b[2];
  #pragma unroll
  for (int c = 0; c < 64; c++) {
    float v = (sh[lane][c] - sm[c]) * sr[c];
    a0 = fmaf(v, W[c*3+0], a0);
    a1 = fmaf(v, W[c*3+1], a1);
    a2 = fmaf(v, W[c*3+2], a2);
  }
  float inv = 1.f / sqrtf(a0*a0 + a1*a1 + a2*a2);
  int n = nb + lane;
  X[n*3+0] = a0 * inv;
  X[n*3+1] = a1 * inv;
  X[n*3+2] = a2 * inv;
}

// ------------- MMD: R16 register-blocked kXX (8 m-points/thread) ----------
__device__ inline float block_reduce_sum(float v) {
  #pragma unroll
  for (int o = 32; o > 0; o >>= 1) v += __shfl_down(v, o, 64);
  __shared__ float red[4];
  int lane = threadIdx.x & 63, w = threadIdx.x >> 6;
  if (lane == 0) red[w] = v;
  __syncthreads();
  float t = 0.f;
  if (threadIdx.x == 0) t = red[0] + red[1] + red[2] + red[3];
  return t;
}

__global__ __launch_bounds__(256) void mmd_kernel(
    const float* __restrict__ X, YArr Y,
    float* __restrict__ kxx, float* __restrict__ kxy)
{
  if (blockIdx.x < 512) {
    int b  = blockIdx.x >> 5;
    int nt = blockIdx.x & 31;
    const float* Xb = X + (size_t)b * NSAMP * 3;
    __shared__ float sx[192];
    if (threadIdx.x < 192) sx[threadIdx.x] = Xb[nt*192 + threadIdx.x];
    __syncthreads();
    float mx0[8], mx1[8], mx2[8], ac[8];
    #pragma unroll
    for (int k = 0; k < 8; k++) {
      int m = k*256 + threadIdx.x;
      mx0[k] = Xb[m*3+0]; mx1[k] = Xb[m*3+1]; mx2[k] = Xb[m*3+2];
      ac[k] = 0.f;
    }
    for (int n = 0; n < 64; n++) {
      float s0 = sx[n*3+0], s1 = sx[n*3+1], s2 = sx[n*3+2];
      #pragma unroll
      for (int k = 0; k < 8; k++) {
        float d = fmaf(mx2[k], s2, fmaf(mx1[k], s1, mx0[k]*s0));
        ac[k] += __expf(2.f*d - 2.f);
      }
    }
    float ps = ((ac[0]+ac[1])+(ac[2]+ac[3])) + ((ac[4]+ac[5])+(ac[6]+ac[7]));
    float t2 = block_reduce_sum(ps);
    if (threadIdx.x == 0) atomicAdd(&kxx[b], t2);
  } else {
    int t  = blockIdx.x - 512;
    int b  = t >> 2;
    int ms = t & 3;
    const float* Xb = X + (size_t)b * NSAMP * 3;
    float ps = 0.f;
    #pragma unroll
    for (int it = 0; it < 2; it++) {
      int n = ms*512 + it*256 + threadIdx.x;
      float x0 = Xb[n*3+0], x1 = Xb[n*3+1], x2 = Xb[n*3+2];
      #pragma unroll
      for (int m = 0; m < 64; m++) {
        float d = x0*Y.v[m*3+0] + x1*Y.v[m*3+1] + x2*Y.v[m*3+2];
        ps += __expf(2.f*d - 2.f);
      }
    }
    float t2 = block_reduce_sum(ps);
    if (threadIdx.x == 0) atomicAdd(&kxy[b], t2);
  }
}

__global__ void loss_kernel(const float* __restrict__ kxx,
                            const float* __restrict__ kxy,
                            float kyy, float* __restrict__ out)
{
  if (threadIdx.x == 0 && blockIdx.x == 0) {
    float s = 0.f;
    for (int b = 0; b < NBATCH; b++)
      s += kxx[b] * (1.0f/((float)NSAMP*(float)NSAMP))
         - 2.0f * kxy[b] * (1.0f/((float)NSAMP*64.0f));
    out[0] = s * (1.0f/NBATCH) + kyy;
  }
}

// ------------- launch -------------
extern "C" void kernel_launch(void* const* d_in, const int* in_sizes, int n_in,
                              void* d_out, int out_size, void* d_ws, size_t ws_size,
                              hipStream_t stream)
{
  const float* x    = (const float*)d_in[0];
  const int*   esrc = (const int*)  d_in[1];
  const int*   edst = (const int*)  d_in[2];
  const float* encW = (const float*)d_in[4];
  const float* encb = (const float*)d_in[5];
  const float* m1W  = (const float*)d_in[6];
  const float* m1b  = (const float*)d_in[7];
  const float* m2W  = (const float*)d_in[8];
  const float* m2b  = (const float*)d_in[9];
  const float* u1W  = (const float*)d_in[10];
  const float* u1b  = (const float*)d_in[11];
  const float* u2W  = (const float*)d_in[12];
  const float* u2b  = (const float*)d_in[13];
  const float* decW = (const float*)d_in[14];
  const float* decb = (const float*)d_in[15];
  float* out = (float*)d_out;

  const size_t NF = (size_t)NNODES * 64;
  // single zero region: [aggAll | statsA | statsB | kxx | kxy | icnt]
  float* aggAll = (float*)d_ws;        // 4 * NF
  float* statsA = aggAll + 4*NF;       // 4096
  float* statsB = statsA + 4096;       // 4096
  float* kxx    = statsB + 4096;       // 16
  float* kxy    = kxx + 16;            // 16 (zeroed; atomicAdd target)
  int*   icnt   = (int*)(kxy + 16);    // 32768
  size_t zero_bytes = (4*NF + 4096 + 4096 + 32) * sizeof(float) + NNODES * sizeof(int);

  float* u_buf  = (float*)(icnt + NNODES);
  float* Pbuf   = u_buf + NF;
  float* Qbuf   = Pbuf + NF;
  float* Rbuf   = Qbuf + NF;
  int* ioffs    = (int*)(Rbuf + NF + 16);   // +16 pad keeps legacy layout offsets
  int* icur     = ioffs + NNODES;
  int* psrc     = icur + NNODES;
  int* pdst     = psrc + NEDGES;
  ushort_t* us  = (ushort_t*)(pdst + NEDGES);
  ushort_t* wc_hi  = us;  us += 4*192*PK2;
  ushort_t* wc_lo  = us;  us += 4*192*PK2;
  ushort_t* w1b_hi = us;  us += 4*64*PK2;
  ushort_t* w1b_lo = us;  us += 4*64*PK2;
  ushort_t* w2e_hi = us;  us += 4*64*PK2;
  ushort_t* w2e_lo = us;  us += 4*64*PK2;
  ushort_t* w2n_hi = us;  us += 4*64*PK2;
  ushort_t* w2n_lo = us;  us += 4*64*PK2;

  float* X = out + 1;

  hipMemsetAsync(aggAll, 0, zero_bytes, stream);

  setup_kernel<<<384 + NEDGES/256, 256, 0, stream>>>(
      m1W, m2W, u1W, u2W,
      wc_hi, wc_lo, w1b_hi, w1b_lo, w2e_hi, w2e_lo, w2n_hi, w2n_lo,
      edst, icnt);
  scan_kernel<<<1, 1024, 0, stream>>>(icnt, ioffs, icur);
  fill_kernel<<<NEDGES/256, 256, 0, stream>>>(esrc, edst, icur, psrc, pdst);

  for (int l = 0; l < 4; l++) {
    const ushort_t* wch = wc_hi + (size_t)l*192*PK2;
    const ushort_t* wcl = wc_lo + (size_t)l*192*PK2;
    if (l == 0)
      norm_pqr_kernel<0><<<512, 256, 0, stream>>>(
          x, nullptr, nullptr, encW, encb, wch, wcl, m1b + l*64,
          Pbuf, Qbuf, Rbuf);
    else
      norm_pqr_kernel<1><<<512, 256, 0, stream>>>(
          u_buf, statsA + (l-1)*1024, statsB + (l-1)*1024, nullptr, nullptr,
          wch, wcl, m1b + l*64, Pbuf, Qbuf, Rbuf);

    edge_fused_kernel<<<768, 256, 0, stream>>>(
        Pbuf, Qbuf, psrc, pdst,
        w2e_hi + (size_t)l*64*PK2, w2e_lo + (size_t)l*64*PK2, m2b + l*64,
        aggAll + (size_t)l*NF);

    node_mfma_kernel<<<512, 256, 0, stream>>>(
        aggAll + (size_t)l*NF, Rbuf,
        w1b_hi + (size_t)l*64*PK2, w1b_lo + (size_t)l*64*PK2, u1b + l*64,
        w2n_hi + (size_t)l*64*PK2, w2n_lo + (size_t)l*64*PK2, u2b + l*64,
        u_buf, statsA + l*1024, statsB + l*1024);
  }

  decoder_kernel<<<NNODES/64, 64, 0, stream>>>(
      u_buf, statsA + 3*1024, statsB + 3*1024, decW, decb, X);

  YArr Y;
  {
    const double pi = 3.14159265358979323846;
    double phi = pi * (3.0 - sqrt(5.0));
    for (int i = 0; i < 64; i++) {
      double y  = 1.0 - 2.0 * (double)i / 63.0;
      double r  = sqrt(fmax(0.0, 1.0 - y*y));
      double th = phi * (double)i;
      Y.v[i*3+0] = (float)(cos(th) * r);
      Y.v[i*3+1] = (float)y;
      Y.v[i*3+2] = (float)(sin(th) * r);
    }
  }
  double kyy_acc = 0.0;
  for (int i = 0; i < 64; i++)
    for (int j = 0; j < 64; j++) {
      double d = (double)Y.v[i*3+0]*Y.v[j*3+0]
               + (double)Y.v[i*3+1]*Y.v[j*3+1]
               + (double)Y.v[i*3+2]*Y.v[j*3+2];
      kyy_acc += exp(2.0*d - 2.0);
    }
  float kyy = (float)(kyy_acc / 4096.0);

  mmd_kernel<<<512 + 64, 256, 0, stream>>>(X, Y, kxx, kxy);
  loss_kernel<<<1, 64, 0, stream>>>(kxx, kxy, kyy, out);
}

// Round 20
// 389.672 us; speedup vs baseline: 1.1012x; 1.0477x over previous
//
#include <hip/hip_runtime.h>
#include <cmath>

#define NNODES 32768
#define NEDGES 524288
#define NBATCH 16
#define NSAMP  2048
#define EPS    1e-5f

#define PK2 72    // 64 + 8 pad (shorts); row stride 144 B (16B-multiple)

typedef short s16x8 __attribute__((ext_vector_type(8)));
typedef float f32x4 __attribute__((ext_vector_type(4)));
typedef unsigned int u32x4 __attribute__((ext_vector_type(4)));
typedef unsigned short ushort_t;

struct YArr { float v[192]; };

static __device__ __forceinline__ unsigned short f2bf(float f) {
  unsigned int u = __float_as_uint(f);
  u = (u + 0x7fffu + ((u >> 16) & 1u)) >> 16;   // RN-even
  return (unsigned short)u;
}
static __device__ __forceinline__ float bf2f(unsigned short b) {
  return __uint_as_float(((unsigned int)b) << 16);
}

// pack two f32 into bf16 hi-pair + residual lo-pair via HW cvt_pk (1 instr per pair)
// ph = [bf16(v1) | bf16(v0)], pl = [bf16(v1-h1) | bf16(v0-h0)]
static __device__ __forceinline__ void pack2(float v0, float v1,
                                             unsigned int& ph, unsigned int& pl) {
  asm("v_cvt_pk_bf16_f32 %0, %1, %2" : "=v"(ph) : "v"(v0), "v"(v1));
  float h0 = __uint_as_float(ph << 16);
  float h1 = __uint_as_float(ph & 0xffff0000u);
  asm("v_cvt_pk_bf16_f32 %0, %1, %2" : "=v"(pl) : "v"(v0 - h0), "v"(v1 - h1));
}

// build an 8-wide bf16 hi/lo fragment from 8 f32 values
static __device__ __forceinline__ void pack8(const float* vv, s16x8& hi, s16x8& lo) {
  unsigned int h0,h1,h2,h3,l0,l1,l2,l3;
  pack2(vv[0], vv[1], h0, l0);
  pack2(vv[2], vv[3], h1, l1);
  pack2(vv[4], vv[5], h2, l2);
  pack2(vv[6], vv[7], h3, l3);
  u32x4 uh = (u32x4){h0, h1, h2, h3};
  u32x4 ul = (u32x4){l0, l1, l2, l3};
  hi = __builtin_bit_cast(s16x8, uh);
  lo = __builtin_bit_cast(s16x8, ul);
}

// ------------- setup: weight prep (blocks 0..383) + CSR count (blocks 384..) ----
__global__ __launch_bounds__(256) void setup_kernel(
    const float* __restrict__ m1W, const float* __restrict__ m2W,
    const float* __restrict__ u1W, const float* __restrict__ u2W,
    ushort_t* __restrict__ wc_hi, ushort_t* __restrict__ wc_lo,
    ushort_t* __restrict__ w1b_hi, ushort_t* __restrict__ w1b_lo,
    ushort_t* __restrict__ w2e_hi, ushort_t* __restrict__ w2e_lo,
    ushort_t* __restrict__ w2n_hi, ushort_t* __restrict__ w2n_lo,
    const int* __restrict__ edst, int* __restrict__ cnt)
{
  if (blockIdx.x >= 384) {
    int e = (blockIdx.x - 384) * 256 + threadIdx.x;
    if (e < NEDGES) atomicAdd(&cnt[edst[e]], 1);
    return;
  }
  int t = blockIdx.x * 256 + threadIdx.x;
  if (t >= 4 * 24576) return;
  int l = t / 24576;
  int r = t % 24576;
  float w; ushort_t *dh, *dl;
  if (r < 12288) {                      // Wcomb: P|Q|R
    int j = r >> 6, k = r & 63;
    if (j < 64)       w = m1W[l*8192 + k*64 + j];
    else if (j < 128) w = m1W[l*8192 + (64 + k)*64 + (j - 64)];
    else              w = u1W[l*8192 + k*64 + (j - 128)];
    int off = l*192*PK2 + j*PK2 + k;
    dh = wc_hi + off; dl = wc_lo + off;
  } else if (r < 16384) {               // W1b
    int idx = r - 12288;
    int j = idx & 63, k = idx >> 6;
    w = u1W[l*8192 + (64 + k)*64 + j];
    int off = l*64*PK2 + j*PK2 + k;
    dh = w1b_hi + off; dl = w1b_lo + off;
  } else if (r < 20480) {               // W2e
    int idx = r - 16384;
    int j = idx & 63, k = idx >> 6;
    w = m2W[l*4096 + k*64 + j];
    int off = l*64*PK2 + j*PK2 + k;
    dh = w2e_hi + off; dl = w2e_lo + off;
  } else {                              // W2n
    int idx = r - 20480;
    int j = idx & 63, k = idx >> 6;
    w = u2W[l*4096 + k*64 + j];
    int off = l*64*PK2 + j*PK2 + k;
    dh = w2n_hi + off; dl = w2n_lo + off;
  }
  unsigned short hb = f2bf(w);
  *dh = hb;
  *dl = f2bf(w - bf2f(hb));
}

__global__ __launch_bounds__(1024) void scan_kernel(const int* __restrict__ cnt,
                                                    int* __restrict__ offs,
                                                    int* __restrict__ cursor) {
  __shared__ int sc[1024];
  int tid = threadIdx.x;
  int base = tid * 32;
  int s = 0;
  #pragma unroll
  for (int i = 0; i < 32; i++) s += cnt[base + i];
  sc[tid] = s; __syncthreads();
  int own = s;
  for (int off = 1; off < 1024; off <<= 1) {
    int v = (tid >= off) ? sc[tid - off] : 0;
    __syncthreads();
    sc[tid] += v;
    __syncthreads();
  }
  int run = sc[tid] - own;
  for (int i = 0; i < 32; i++) {
    offs[base + i] = run; cursor[base + i] = run;
    run += cnt[base + i];
  }
}

__global__ __launch_bounds__(256) void fill_kernel(
    const int* __restrict__ esrc, const int* __restrict__ edst,
    int* __restrict__ cursor, int* __restrict__ psrc, int* __restrict__ pdst) {
  int e = blockIdx.x * 256 + threadIdx.x;
  if (e < NEDGES) {
    int d = edst[e];
    int pos = atomicAdd(&cursor[d], 1);
    psrc[pos] = esrc[e];
    pdst[pos] = d;
  }
}

// ------------- fused (encode|norm) + P|Q|R GEMM -------------
// R18: direct A-fragment build (no staging LDS). MODE 1: float4x2 row load +
// per-column mean/rstd via __shfl from the owning lane (register-only).
// MODE 0: encode computed per fragment column from L2-hot encW row vectors.
// Values arithmetically identical to the staged path. b1 folded into P (R17).
template<int MODE>
__global__ __launch_bounds__(256) void norm_pqr_kernel(
    const float* __restrict__ in,     // x (MODE 0) or u (MODE 1)
    const float* __restrict__ sA, const float* __restrict__ sB,
    const float* __restrict__ encW, const float* __restrict__ encb,
    const ushort_t* __restrict__ Wh, const ushort_t* __restrict__ Wl,
    const float* __restrict__ b1e,
    float* __restrict__ P, float* __restrict__ Q, float* __restrict__ Rb)
{
  int tid = threadIdx.x, lane = tid & 63, wave = tid >> 6;
  int l15 = lane & 15, quad = lane >> 4;
  int base = blockIdx.x * 64 + wave * 16;
  int g = blockIdx.x >> 5;
  int row = base + l15;

  s16x8 ah[2], al[2];

  if (MODE) {
    // per-lane (feature = lane) stats, fragment cols fetched via shfl
    float a = sA[g*64 + lane], q = sB[g*64 + lane];
    float mean = a * (1.f / NSAMP);
    float var = q * (1.f / NSAMP) - mean * mean;
    float rstd = rsqrtf(var + EPS);
    #pragma unroll
    for (int kb = 0; kb < 2; kb++) {
      const float* up = in + (size_t)row*64 + kb*32 + quad*8;
      float4 u0 = *(const float4*)(up);
      float4 u1 = *(const float4*)(up + 4);
      float uv[8] = {u0.x,u0.y,u0.z,u0.w,u1.x,u1.y,u1.z,u1.w};
      int cbs = kb*32 + quad*8;
      float vv[8];
      #pragma unroll
      for (int j = 0; j < 8; j++) {
        float mc = __shfl(mean, cbs + j);
        float rc = __shfl(rstd, cbs + j);
        vv[j] = (uv[j] - mc) * rc;
      }
      pack8(vv, ah[kb], al[kb]);
    }
  } else {
    float x0 = in[row*3+0], x1 = in[row*3+1], x2 = in[row*3+2];
    #pragma unroll
    for (int kb = 0; kb < 2; kb++) {
      int cbs = kb*32 + quad*8;
      float4 e0a = *(const float4*)(encW + cbs);
      float4 e0b = *(const float4*)(encW + cbs + 4);
      float4 e1a = *(const float4*)(encW + 64 + cbs);
      float4 e1b = *(const float4*)(encW + 64 + cbs + 4);
      float4 e2a = *(const float4*)(encW + 128 + cbs);
      float4 e2b = *(const float4*)(encW + 128 + cbs + 4);
      float4 eba = *(const float4*)(encb + cbs);
      float4 ebb = *(const float4*)(encb + cbs + 4);
      float w0v[8] = {e0a.x,e0a.y,e0a.z,e0a.w,e0b.x,e0b.y,e0b.z,e0b.w};
      float w1v[8] = {e1a.x,e1a.y,e1a.z,e1a.w,e1b.x,e1b.y,e1b.z,e1b.w};
      float w2v[8] = {e2a.x,e2a.y,e2a.z,e2a.w,e2b.x,e2b.y,e2b.z,e2b.w};
      float bbv[8] = {eba.x,eba.y,eba.z,eba.w,ebb.x,ebb.y,ebb.z,ebb.w};
      float vv[8];
      #pragma unroll
      for (int j = 0; j < 8; j++)
        vv[j] = fmaf(x2, w2v[j], fmaf(x1, w1v[j], fmaf(x0, w0v[j], bbv[j])));
      pack8(vv, ah[kb], al[kb]);
    }
  }

  #pragma unroll
  for (int ct = 0; ct < 12; ct++) {
    f32x4 acc = (f32x4){0.f, 0.f, 0.f, 0.f};
    #pragma unroll
    for (int kb = 0; kb < 2; kb++) {
      int woff = (ct*16 + l15)*PK2 + kb*32 + quad*8;
      s16x8 bh = *(const s16x8*)(Wh + woff);
      s16x8 bl = *(const s16x8*)(Wl + woff);
      // bf16x3: drop al*bl (≤2^-18 relative ≈ 4e-6 per term)
      acc = __builtin_amdgcn_mfma_f32_16x16x32_bf16(al[kb], bh, acc, 0, 0, 0);
      acc = __builtin_amdgcn_mfma_f32_16x16x32_bf16(ah[kb], bl, acc, 0, 0, 0);
      acc = __builtin_amdgcn_mfma_f32_16x16x32_bf16(ah[kb], bh, acc, 0, 0, 0);
    }
    int j = ct*16 + l15;
    float* dst; int jj; float addv = 0.f;
    if (ct < 4)      { dst = P;  jj = j; addv = b1e[jj]; }
    else if (ct < 8) { dst = Q;  jj = j - 64; }
    else             { dst = Rb; jj = j - 128; }
    #pragma unroll
    for (int rr = 0; rr < 4; rr++) {
      int rw = base + quad*4 + rr;
      dst[(size_t)rw*64 + jj] = acc[rr] + addv;
    }
  }
}

// ------------- fused edge MLP + segment-reduce (grid 768) --------
// R17: direct-fragment gather — each lane loads its MFMA fragment rows
// straight from P/Q (float4 x2 per row), packs hi/lo in-register via cvt_pk.
__global__ __launch_bounds__(256, 3) void edge_fused_kernel(
    const float* __restrict__ Pbuf, const float* __restrict__ Qbuf,
    const int* __restrict__ psrc, const int* __restrict__ pdst,
    const ushort_t* __restrict__ W2hi, const ushort_t* __restrict__ W2lo,
    const float* __restrict__ b2,
    float* __restrict__ agg)
{
  __shared__ __align__(16) float m2s[4][32*68];
  __shared__ int sSDb[2][4][64];

  int tid = threadIdx.x;
  int lane = tid & 63, wave = tid >> 6;
  int l15 = lane & 15, quad = lane >> 4;

  float* m2 = m2s[wave];

  s16x8 w2h[2][4], w2l[2][4];
  #pragma unroll
  for (int kb = 0; kb < 2; kb++)
    #pragma unroll
    for (int ct = 0; ct < 4; ct++) {
      int off = (ct*16 + l15)*PK2 + kb*32 + quad*8;
      w2h[kb][ct] = *(const s16x8*)(W2hi + off);
      w2l[kb][ct] = *(const s16x8*)(W2lo + off);
    }
  float b2v[4];
  #pragma unroll
  for (int ct = 0; ct < 4; ct++) b2v[ct] = b2[ct*16 + l15];

  const int* tb = (lane < 32) ? psrc : pdst;
  int lidx = lane & 31;
  int step = gridDim.x * 128;
  int base0 = blockIdx.x * 128;

  int sidx = tb[base0 + wave*32 + lidx];
  sSDb[0][wave][lane] = sidx;

  int cb = 0;
  for (int base = base0; base < NEDGES; base += step) {
    const int* sc = sSDb[cb][wave];
    int nb = base + step;
    int havenext = nb < NEDGES;
    if (havenext) sidx = tb[nb + wave*32 + lidx];   // index prefetch

    // direct fragment gather + in-register hi/lo pack
    s16x8 pah[2][2], pal[2][2];     // [kb][rt]
    #pragma unroll
    for (int kb = 0; kb < 2; kb++) {
      float4 qq[2][2], pp[2][2];    // [rt][half] — 8 loads in flight per kb
      #pragma unroll
      for (int rt = 0; rt < 2; rt++) {
        int srow = sc[rt*16 + l15];
        int drow = sc[32 + rt*16 + l15];
        const float* qp = Qbuf + (((size_t)srow) << 6) + kb*32 + quad*8;
        const float* pd = Pbuf + (((size_t)drow) << 6) + kb*32 + quad*8;
        qq[rt][0] = *(const float4*)(qp);
        qq[rt][1] = *(const float4*)(qp + 4);
        pp[rt][0] = *(const float4*)(pd);
        pp[rt][1] = *(const float4*)(pd + 4);
      }
      #pragma unroll
      for (int rt = 0; rt < 2; rt++) {
        float vv[8];
        vv[0] = fmaxf(pp[rt][0].x + qq[rt][0].x, 0.f);
        vv[1] = fmaxf(pp[rt][0].y + qq[rt][0].y, 0.f);
        vv[2] = fmaxf(pp[rt][0].z + qq[rt][0].z, 0.f);
        vv[3] = fmaxf(pp[rt][0].w + qq[rt][0].w, 0.f);
        vv[4] = fmaxf(pp[rt][1].x + qq[rt][1].x, 0.f);
        vv[5] = fmaxf(pp[rt][1].y + qq[rt][1].y, 0.f);
        vv[6] = fmaxf(pp[rt][1].z + qq[rt][1].z, 0.f);
        vv[7] = fmaxf(pp[rt][1].w + qq[rt][1].w, 0.f);
        pack8(vv, pah[kb][rt], pal[kb][rt]);
      }
    }

    f32x4 facc[2][4];
    #pragma unroll
    for (int rt = 0; rt < 2; rt++)
      #pragma unroll
      for (int ct = 0; ct < 4; ct++)
        facc[rt][ct] = (f32x4){0.f, 0.f, 0.f, 0.f};

    #pragma unroll
    for (int kb = 0; kb < 2; kb++)
      #pragma unroll
      for (int ct = 0; ct < 4; ct++)
        #pragma unroll
        for (int rt = 0; rt < 2; rt++) {
          // bf16x3: drop pal*w2l
          facc[rt][ct] = __builtin_amdgcn_mfma_f32_16x16x32_bf16(pal[kb][rt], w2h[kb][ct], facc[rt][ct], 0, 0, 0);
          facc[rt][ct] = __builtin_amdgcn_mfma_f32_16x16x32_bf16(pah[kb][rt], w2l[kb][ct], facc[rt][ct], 0, 0, 0);
          facc[rt][ct] = __builtin_amdgcn_mfma_f32_16x16x32_bf16(pah[kb][rt], w2h[kb][ct], facc[rt][ct], 0, 0, 0);
        }

    // stage next tile's indices during m2-write + reduce + atomics
    if (havenext) sSDb[cb ^ 1][wave][lane] = sidx;

    #pragma unroll
    for (int rt = 0; rt < 2; rt++)
      #pragma unroll
      for (int ct = 0; ct < 4; ct++)
        #pragma unroll
        for (int r = 0; r < 4; r++)
          m2[(rt*16 + quad*4 + r)*68 + ct*16 + l15] = fmaxf(facc[rt][ct][r] + b2v[ct], 0.f);

    // serial 32-row segment reduce (measured-good form)
    int curd = sc[32];
    float acc = 0.f;
    #pragma unroll
    for (int r = 0; r < 32; r++) {
      int d = sc[32 + r];
      float v = m2[r*68 + lane];
      if (d != curd) {
        unsafeAtomicAdd(&agg[((size_t)curd << 6) + lane], acc);
        acc = 0.f; curd = d;
      }
      acc += v;
    }
    unsafeAtomicAdd(&agg[((size_t)curd << 6) + lane], acc);

    cb ^= 1;
  }
}

// ------------- node MLP -------------
__global__ __launch_bounds__(256) void node_mfma_kernel(
    const float* __restrict__ aggF, const float* __restrict__ Rbuf,
    const ushort_t* __restrict__ W1h, const ushort_t* __restrict__ W1l,
    const float* __restrict__ b1,
    const ushort_t* __restrict__ W2h, const ushort_t* __restrict__ W2l,
    const float* __restrict__ b2,
    float* __restrict__ uout, float* __restrict__ sA, float* __restrict__ sB)
{
  __shared__ __align__(16) ushort_t sMh[4][16*PK2];
  __shared__ __align__(16) ushort_t sMl[4][16*PK2];
  int tid = threadIdx.x, lane = tid & 63, wave = tid >> 6;
  int l15 = lane & 15, quad = lane >> 4;
  int base = blockIdx.x * 64 + wave * 16;
  int g = blockIdx.x >> 5;

  s16x8 ah[2], al[2];
  {
    int em = base + l15;
    #pragma unroll
    for (int kb = 0; kb < 2; kb++) {
      size_t off = (size_t)em*64 + kb*32 + quad*8;
      float4 v0 = *(const float4*)(aggF + off);
      float4 v1 = *(const float4*)(aggF + off + 4);
      float vv[8] = {v0.x,v0.y,v0.z,v0.w,v1.x,v1.y,v1.z,v1.w};
      pack8(vv, ah[kb], al[kb]);
    }
  }

  ushort_t* mh = sMh[wave];
  ushort_t* ml = sMl[wave];
  float b1v[4], b2v[4];
  #pragma unroll
  for (int ct = 0; ct < 4; ct++) { b1v[ct] = b1[ct*16+l15]; b2v[ct] = b2[ct*16+l15]; }

  #pragma unroll
  for (int ct = 0; ct < 4; ct++) {
    f32x4 acc = (f32x4){0.f, 0.f, 0.f, 0.f};
    #pragma unroll
    for (int kb = 0; kb < 2; kb++) {
      int woff = (ct*16 + l15)*PK2 + kb*32 + quad*8;
      s16x8 bh = *(const s16x8*)(W1h + woff);
      s16x8 bl = *(const s16x8*)(W1l + woff);
      // bf16x3: drop al*bl
      acc = __builtin_amdgcn_mfma_f32_16x16x32_bf16(al[kb], bh, acc, 0, 0, 0);
      acc = __builtin_amdgcn_mfma_f32_16x16x32_bf16(ah[kb], bl, acc, 0, 0, 0);
      acc = __builtin_amdgcn_mfma_f32_16x16x32_bf16(ah[kb], bh, acc, 0, 0, 0);
    }
    int j = ct*16 + l15;
    #pragma unroll
    for (int rr = 0; rr < 4; rr += 2) {
      int row = quad*4 + rr;
      float v0 = fmaxf(acc[rr]   + Rbuf[(size_t)(base+row)*64   + j] + b1v[ct], 0.f);
      float v1 = fmaxf(acc[rr+1] + Rbuf[(size_t)(base+row+1)*64 + j] + b1v[ct], 0.f);
      unsigned int ph, pl;
      pack2(v0, v1, ph, pl);
      mh[row*PK2 + j]     = (ushort_t)(ph & 0xffffu);
      mh[(row+1)*PK2 + j] = (ushort_t)(ph >> 16);
      ml[row*PK2 + j]     = (ushort_t)(pl & 0xffffu);
      ml[(row+1)*PK2 + j] = (ushort_t)(pl >> 16);
    }
  }

  s16x8 mhf[2], mlf[2];
  #pragma unroll
  for (int kb = 0; kb < 2; kb++) {
    int idx = l15*PK2 + kb*32 + quad*8;
    mhf[kb] = *(const s16x8*)&mh[idx];
    mlf[kb] = *(const s16x8*)&ml[idx];
  }
  #pragma unroll
  for (int ct = 0; ct < 4; ct++) {
    f32x4 facc = (f32x4){0.f, 0.f, 0.f, 0.f};
    #pragma unroll
    for (int kb = 0; kb < 2; kb++) {
      int woff = (ct*16 + l15)*PK2 + kb*32 + quad*8;
      s16x8 bh = *(const s16x8*)(W2h + woff);
      s16x8 bl = *(const s16x8*)(W2l + woff);
      // bf16x3: drop mlf*bl
      facc = __builtin_amdgcn_mfma_f32_16x16x32_bf16(mlf[kb], bh, facc, 0, 0, 0);
      facc = __builtin_amdgcn_mfma_f32_16x16x32_bf16(mhf[kb], bl, facc, 0, 0, 0);
      facc = __builtin_amdgcn_mfma_f32_16x16x32_bf16(mhf[kb], bh, facc, 0, 0, 0);
    }
    int j = ct*16 + l15;
    float s = 0.f, s2 = 0.f;
    #pragma unroll
    for (int rr = 0; rr < 4; rr++) {
      int row = quad*4 + rr;
      float v = fmaxf(facc[rr] + b2v[ct], 0.f);
      uout[(size_t)(base+row)*64 + j] = v;
      s += v; s2 += v*v;
    }
    s  += __shfl_xor(s, 16);  s  += __shfl_xor(s, 32);
    s2 += __shfl_xor(s2, 16); s2 += __shfl_xor(s2, 32);
    if (quad == 0) {
      unsafeAtomicAdd(&sA[g*64 + j], s);
      unsafeAtomicAdd(&sB[g*64 + j], s2);
    }
  }
}

// ------------- decoder -------------
__global__ __launch_bounds__(64) void decoder_kernel(
    const float* __restrict__ u, const float* __restrict__ sA,
    const float* __restrict__ sB, const float* __restrict__ W,
    const float* __restrict__ b, float* __restrict__ X)
{
  __shared__ float sh[64][65];
  __shared__ float sm[64], sr[64];
  int lane = threadIdx.x;
  int nb = blockIdx.x * 64;
  int g = blockIdx.x >> 5;
  {
    float a = sA[g*64 + lane], q = sB[g*64 + lane];
    float mean = a * (1.f / NSAMP);
    float var = q * (1.f / NSAMP) - mean * mean;
    sm[lane] = mean;
    sr[lane] = rsqrtf(var + EPS);
  }
  for (int r = 0; r < 64; r++) sh[r][lane] = u[(size_t)(nb + r) * 64 + lane];
  __syncthreads();
  float a0 = b[0], a1 = b[1], a2 = b[2];
  #pragma unroll
  for (int c = 0; c < 64; c++) {
    float v = (sh[lane][c] - sm[c]) * sr[c];
    a0 = fmaf(v, W[c*3+0], a0);
    a1 = fmaf(v, W[c*3+1], a1);
    a2 = fmaf(v, W[c*3+2], a2);
  }
  float inv = 1.f / sqrtf(a0*a0 + a1*a1 + a2*a2);
  int n = nb + lane;
  X[n*3+0] = a0 * inv;
  X[n*3+1] = a1 * inv;
  X[n*3+2] = a2 * inv;
}

// ------------- MMD: R16 register-blocked kXX (8 m-points/thread) ----------
__device__ inline float block_reduce_sum(float v) {
  #pragma unroll
  for (int o = 32; o > 0; o >>= 1) v += __shfl_down(v, o, 64);
  __shared__ float red[4];
  int lane = threadIdx.x & 63, w = threadIdx.x >> 6;
  if (lane == 0) red[w] = v;
  __syncthreads();
  float t = 0.f;
  if (threadIdx.x == 0) t = red[0] + red[1] + red[2] + red[3];
  return t;
}

__global__ __launch_bounds__(256) void mmd_kernel(
    const float* __restrict__ X, YArr Y,
    float* __restrict__ kxx, float* __restrict__ kxy)
{
  if (blockIdx.x < 512) {
    int b  = blockIdx.x >> 5;
    int nt = blockIdx.x & 31;
    const float* Xb = X + (size_t)b * NSAMP * 3;
    __shared__ float sx[192];
    if (threadIdx.x < 192) sx[threadIdx.x] = Xb[nt*192 + threadIdx.x];
    __syncthreads();
    float mx0[8], mx1[8], mx2[8], ac[8];
    #pragma unroll
    for (int k = 0; k < 8; k++) {
      int m = k*256 + threadIdx.x;
      mx0[k] = Xb[m*3+0]; mx1[k] = Xb[m*3+1]; mx2[k] = Xb[m*3+2];
      ac[k] = 0.f;
    }
    for (int n = 0; n < 64; n++) {
      float s0 = sx[n*3+0], s1 = sx[n*3+1], s2 = sx[n*3+2];
      #pragma unroll
      for (int k = 0; k < 8; k++) {
        float d = fmaf(mx2[k], s2, fmaf(mx1[k], s1, mx0[k]*s0));
        ac[k] += __expf(2.f*d - 2.f);
      }
    }
    float ps = ((ac[0]+ac[1])+(ac[2]+ac[3])) + ((ac[4]+ac[5])+(ac[6]+ac[7]));
    float t2 = block_reduce_sum(ps);
    if (threadIdx.x == 0) atomicAdd(&kxx[b], t2);
  } else {
    int t  = blockIdx.x - 512;
    int b  = t >> 2;
    int ms = t & 3;
    const float* Xb = X + (size_t)b * NSAMP * 3;
    float ps = 0.f;
    #pragma unroll
    for (int it = 0; it < 2; it++) {
      int n = ms*512 + it*256 + threadIdx.x;
      float x0 = Xb[n*3+0], x1 = Xb[n*3+1], x2 = Xb[n*3+2];
      #pragma unroll
      for (int m = 0; m < 64; m++) {
        float d = x0*Y.v[m*3+0] + x1*Y.v[m*3+1] + x2*Y.v[m*3+2];
        ps += __expf(2.f*d - 2.f);
      }
    }
    float t2 = block_reduce_sum(ps);
    if (threadIdx.x == 0) atomicAdd(&kxy[b], t2);
  }
}

__global__ void loss_kernel(const float* __restrict__ kxx,
                            const float* __restrict__ kxy,
                            float kyy, float* __restrict__ out)
{
  if (threadIdx.x == 0 && blockIdx.x == 0) {
    float s = 0.f;
    for (int b = 0; b < NBATCH; b++)
      s += kxx[b] * (1.0f/((float)NSAMP*(float)NSAMP))
         - 2.0f * kxy[b] * (1.0f/((float)NSAMP*64.0f));
    out[0] = s * (1.0f/NBATCH) + kyy;
  }
}

// ------------- launch -------------
extern "C" void kernel_launch(void* const* d_in, const int* in_sizes, int n_in,
                              void* d_out, int out_size, void* d_ws, size_t ws_size,
                              hipStream_t stream)
{
  const float* x    = (const float*)d_in[0];
  const int*   esrc = (const int*)  d_in[1];
  const int*   edst = (const int*)  d_in[2];
  const float* encW = (const float*)d_in[4];
  const float* encb = (const float*)d_in[5];
  const float* m1W  = (const float*)d_in[6];
  const float* m1b  = (const float*)d_in[7];
  const float* m2W  = (const float*)d_in[8];
  const float* m2b  = (const float*)d_in[9];
  const float* u1W  = (const float*)d_in[10];
  const float* u1b  = (const float*)d_in[11];
  const float* u2W  = (const float*)d_in[12];
  const float* u2b  = (const float*)d_in[13];
  const float* decW = (const float*)d_in[14];
  const float* decb = (const float*)d_in[15];
  float* out = (float*)d_out;

  const size_t NF = (size_t)NNODES * 64;
  // single zero region: [aggAll | statsA | statsB | kxx | kxy | icnt]
  float* aggAll = (float*)d_ws;        // 4 * NF
  float* statsA = aggAll + 4*NF;       // 4096
  float* statsB = statsA + 4096;       // 4096
  float* kxx    = statsB + 4096;       // 16
  float* kxy    = kxx + 16;            // 16 (zeroed; atomicAdd target)
  int*   icnt   = (int*)(kxy + 16);    // 32768
  size_t zero_bytes = (4*NF + 4096 + 4096 + 32) * sizeof(float) + NNODES * sizeof(int);

  float* u_buf  = (float*)(icnt + NNODES);
  float* Pbuf   = u_buf + NF;
  float* Qbuf   = Pbuf + NF;
  float* Rbuf   = Qbuf + NF;
  int* ioffs    = (int*)(Rbuf + NF + 16);   // +16 pad keeps legacy layout offsets
  int* icur     = ioffs + NNODES;
  int* psrc     = icur + NNODES;
  int* pdst     = psrc + NEDGES;
  ushort_t* us  = (ushort_t*)(pdst + NEDGES);
  ushort_t* wc_hi  = us;  us += 4*192*PK2;
  ushort_t* wc_lo  = us;  us += 4*192*PK2;
  ushort_t* w1b_hi = us;  us += 4*64*PK2;
  ushort_t* w1b_lo = us;  us += 4*64*PK2;
  ushort_t* w2e_hi = us;  us += 4*64*PK2;
  ushort_t* w2e_lo = us;  us += 4*64*PK2;
  ushort_t* w2n_hi = us;  us += 4*64*PK2;
  ushort_t* w2n_lo = us;  us += 4*64*PK2;

  float* X = out + 1;

  hipMemsetAsync(aggAll, 0, zero_bytes, stream);

  setup_kernel<<<384 + NEDGES/256, 256, 0, stream>>>(
      m1W, m2W, u1W, u2W,
      wc_hi, wc_lo, w1b_hi, w1b_lo, w2e_hi, w2e_lo, w2n_hi, w2n_lo,
      edst, icnt);
  scan_kernel<<<1, 1024, 0, stream>>>(icnt, ioffs, icur);
  fill_kernel<<<NEDGES/256, 256, 0, stream>>>(esrc, edst, icur, psrc, pdst);

  for (int l = 0; l < 4; l++) {
    const ushort_t* wch = wc_hi + (size_t)l*192*PK2;
    const ushort_t* wcl = wc_lo + (size_t)l*192*PK2;
    if (l == 0)
      norm_pqr_kernel<0><<<512, 256, 0, stream>>>(
          x, nullptr, nullptr, encW, encb, wch, wcl, m1b + l*64,
          Pbuf, Qbuf, Rbuf);
    else
      norm_pqr_kernel<1><<<512, 256, 0, stream>>>(
          u_buf, statsA + (l-1)*1024, statsB + (l-1)*1024, nullptr, nullptr,
          wch, wcl, m1b + l*64, Pbuf, Qbuf, Rbuf);

    edge_fused_kernel<<<768, 256, 0, stream>>>(
        Pbuf, Qbuf, psrc, pdst,
        w2e_hi + (size_t)l*64*PK2, w2e_lo + (size_t)l*64*PK2, m2b + l*64,
        aggAll + (size_t)l*NF);

    node_mfma_kernel<<<512, 256, 0, stream>>>(
        aggAll + (size_t)l*NF, Rbuf,
        w1b_hi + (size_t)l*64*PK2, w1b_lo + (size_t)l*64*PK2, u1b + l*64,
        w2n_hi + (size_t)l*64*PK2, w2n_lo + (size_t)l*64*PK2, u2b + l*64,
        u_buf, statsA + l*1024, statsB + l*1024);
  }

  decoder_kernel<<<NNODES/64, 64, 0, stream>>>(
      u_buf, statsA + 3*1024, statsB + 3*1024, decW, decb, X);

  YArr Y;
  {
    const double pi = 3.14159265358979323846;
    double phi = pi * (3.0 - sqrt(5.0));
    for (int i = 0; i < 64; i++) {
      double y  = 1.0 - 2.0 * (double)i / 63.0;
      double r  = sqrt(fmax(0.0, 1.0 - y*y));
      double th = phi * (double)i;
      Y.v[i*3+0] = (float)(cos(th) * r);
      Y.v[i*3+1] = (float)y;
      Y.v[i*3+2] = (float)(sin(th) * r);
    }
  }
  double kyy_acc = 0.0;
  for (int i = 0; i < 64; i++)
    for (int j = 0; j < 64; j++) {
      double d = (double)Y.v[i*3+0]*Y.v[j*3+0]
               + (double)Y.v[i*3+1]*Y.v[j*3+1]
               + (double)Y.v[i*3+2]*Y.v[j*3+2];
      kyy_acc += exp(2.0*d - 2.0);
    }
  float kyy = (float)(kyy_acc / 4096.0);

  mmd_kernel<<<512 + 64, 256, 0, stream>>>(X, Y, kxx, kxy);
  loss_kernel<<<1, 64, 0, stream>>>(kxx, kxy, kyy, out);
}

// Round 21
// 388.070 us; speedup vs baseline: 1.1057x; 1.0041x over previous
//
#include <hip/hip_runtime.h>
#include <cmath>

#define NNODES 32768
#define NEDGES 524288
#define NBATCH 16
#define NSAMP  2048
#define EPS    1e-5f

#define PK2 72    // 64 + 8 pad (shorts); row stride 144 B (16B-multiple)

typedef short s16x8 __attribute__((ext_vector_type(8)));
typedef float f32x4 __attribute__((ext_vector_type(4)));
typedef unsigned int u32x4 __attribute__((ext_vector_type(4)));
typedef unsigned short ushort_t;

struct YArr { float v[192]; };

static __device__ __forceinline__ unsigned short f2bf(float f) {
  unsigned int u = __float_as_uint(f);
  u = (u + 0x7fffu + ((u >> 16) & 1u)) >> 16;   // RN-even
  return (unsigned short)u;
}
static __device__ __forceinline__ float bf2f(unsigned short b) {
  return __uint_as_float(((unsigned int)b) << 16);
}

// pack two f32 into bf16 hi-pair + residual lo-pair via HW cvt_pk (1 instr per pair)
// ph = [bf16(v1) | bf16(v0)], pl = [bf16(v1-h1) | bf16(v0-h0)]
static __device__ __forceinline__ void pack2(float v0, float v1,
                                             unsigned int& ph, unsigned int& pl) {
  asm("v_cvt_pk_bf16_f32 %0, %1, %2" : "=v"(ph) : "v"(v0), "v"(v1));
  float h0 = __uint_as_float(ph << 16);
  float h1 = __uint_as_float(ph & 0xffff0000u);
  asm("v_cvt_pk_bf16_f32 %0, %1, %2" : "=v"(pl) : "v"(v0 - h0), "v"(v1 - h1));
}

// build an 8-wide bf16 hi/lo fragment from 8 f32 values
static __device__ __forceinline__ void pack8(const float* vv, s16x8& hi, s16x8& lo) {
  unsigned int h0,h1,h2,h3,l0,l1,l2,l3;
  pack2(vv[0], vv[1], h0, l0);
  pack2(vv[2], vv[3], h1, l1);
  pack2(vv[4], vv[5], h2, l2);
  pack2(vv[6], vv[7], h3, l3);
  u32x4 uh = (u32x4){h0, h1, h2, h3};
  u32x4 ul = (u32x4){l0, l1, l2, l3};
  hi = __builtin_bit_cast(s16x8, uh);
  lo = __builtin_bit_cast(s16x8, ul);
}

// ------------- setup: weight prep (blocks 0..383) + CSR count (blocks 384..) ----
__global__ __launch_bounds__(256) void setup_kernel(
    const float* __restrict__ m1W, const float* __restrict__ m2W,
    const float* __restrict__ u1W, const float* __restrict__ u2W,
    ushort_t* __restrict__ wc_hi, ushort_t* __restrict__ wc_lo,
    ushort_t* __restrict__ w1b_hi, ushort_t* __restrict__ w1b_lo,
    ushort_t* __restrict__ w2e_hi, ushort_t* __restrict__ w2e_lo,
    ushort_t* __restrict__ w2n_hi, ushort_t* __restrict__ w2n_lo,
    const int* __restrict__ edst, int* __restrict__ cnt)
{
  if (blockIdx.x >= 384) {
    int e = (blockIdx.x - 384) * 256 + threadIdx.x;
    if (e < NEDGES) atomicAdd(&cnt[edst[e]], 1);
    return;
  }
  int t = blockIdx.x * 256 + threadIdx.x;
  if (t >= 4 * 24576) return;
  int l = t / 24576;
  int r = t % 24576;
  float w; ushort_t *dh, *dl;
  if (r < 12288) {                      // Wcomb: P|Q|R
    int j = r >> 6, k = r & 63;
    if (j < 64)       w = m1W[l*8192 + k*64 + j];
    else if (j < 128) w = m1W[l*8192 + (64 + k)*64 + (j - 64)];
    else              w = u1W[l*8192 + k*64 + (j - 128)];
    int off = l*192*PK2 + j*PK2 + k;
    dh = wc_hi + off; dl = wc_lo + off;
  } else if (r < 16384) {               // W1b
    int idx = r - 12288;
    int j = idx & 63, k = idx >> 6;
    w = u1W[l*8192 + (64 + k)*64 + j];
    int off = l*64*PK2 + j*PK2 + k;
    dh = w1b_hi + off; dl = w1b_lo + off;
  } else if (r < 20480) {               // W2e
    int idx = r - 16384;
    int j = idx & 63, k = idx >> 6;
    w = m2W[l*4096 + k*64 + j];
    int off = l*64*PK2 + j*PK2 + k;
    dh = w2e_hi + off; dl = w2e_lo + off;
  } else {                              // W2n
    int idx = r - 20480;
    int j = idx & 63, k = idx >> 6;
    w = u2W[l*4096 + k*64 + j];
    int off = l*64*PK2 + j*PK2 + k;
    dh = w2n_hi + off; dl = w2n_lo + off;
  }
  unsigned short hb = f2bf(w);
  *dh = hb;
  *dl = f2bf(w - bf2f(hb));
}

__global__ __launch_bounds__(1024) void scan_kernel(const int* __restrict__ cnt,
                                                    int* __restrict__ offs,
                                                    int* __restrict__ cursor) {
  __shared__ int sc[1024];
  int tid = threadIdx.x;
  int base = tid * 32;
  int s = 0;
  #pragma unroll
  for (int i = 0; i < 32; i++) s += cnt[base + i];
  sc[tid] = s; __syncthreads();
  int own = s;
  for (int off = 1; off < 1024; off <<= 1) {
    int v = (tid >= off) ? sc[tid - off] : 0;
    __syncthreads();
    sc[tid] += v;
    __syncthreads();
  }
  int run = sc[tid] - own;
  for (int i = 0; i < 32; i++) {
    offs[base + i] = run; cursor[base + i] = run;
    run += cnt[base + i];
  }
}

__global__ __launch_bounds__(256) void fill_kernel(
    const int* __restrict__ esrc, const int* __restrict__ edst,
    int* __restrict__ cursor, int* __restrict__ psrc, int* __restrict__ pdst) {
  int e = blockIdx.x * 256 + threadIdx.x;
  if (e < NEDGES) {
    int d = edst[e];
    int pos = atomicAdd(&cursor[d], 1);
    psrc[pos] = esrc[e];
    pdst[pos] = d;
  }
}

// ------------- fused (encode|norm) + P|Q|R GEMM -------------
// R18: direct A-fragment build (no staging LDS). MODE 1: float4x2 row load +
// per-column mean/rstd via __shfl from the owning lane (register-only).
// MODE 0: encode computed per fragment column from L2-hot encW row vectors.
template<int MODE>
__global__ __launch_bounds__(256) void norm_pqr_kernel(
    const float* __restrict__ in,     // x (MODE 0) or u (MODE 1)
    const float* __restrict__ sA, const float* __restrict__ sB,
    const float* __restrict__ encW, const float* __restrict__ encb,
    const ushort_t* __restrict__ Wh, const ushort_t* __restrict__ Wl,
    const float* __restrict__ b1e,
    float* __restrict__ P, float* __restrict__ Q, float* __restrict__ Rb)
{
  int tid = threadIdx.x, lane = tid & 63, wave = tid >> 6;
  int l15 = lane & 15, quad = lane >> 4;
  int base = blockIdx.x * 64 + wave * 16;
  int g = blockIdx.x >> 5;
  int row = base + l15;

  s16x8 ah[2], al[2];

  if (MODE) {
    // per-lane (feature = lane) stats, fragment cols fetched via shfl
    float a = sA[g*64 + lane], q = sB[g*64 + lane];
    float mean = a * (1.f / NSAMP);
    float var = q * (1.f / NSAMP) - mean * mean;
    float rstd = rsqrtf(var + EPS);
    #pragma unroll
    for (int kb = 0; kb < 2; kb++) {
      const float* up = in + (size_t)row*64 + kb*32 + quad*8;
      float4 u0 = *(const float4*)(up);
      float4 u1 = *(const float4*)(up + 4);
      float uv[8] = {u0.x,u0.y,u0.z,u0.w,u1.x,u1.y,u1.z,u1.w};
      int cbs = kb*32 + quad*8;
      float vv[8];
      #pragma unroll
      for (int j = 0; j < 8; j++) {
        float mc = __shfl(mean, cbs + j);
        float rc = __shfl(rstd, cbs + j);
        vv[j] = (uv[j] - mc) * rc;
      }
      pack8(vv, ah[kb], al[kb]);
    }
  } else {
    float x0 = in[row*3+0], x1 = in[row*3+1], x2 = in[row*3+2];
    #pragma unroll
    for (int kb = 0; kb < 2; kb++) {
      int cbs = kb*32 + quad*8;
      float4 e0a = *(const float4*)(encW + cbs);
      float4 e0b = *(const float4*)(encW + cbs + 4);
      float4 e1a = *(const float4*)(encW + 64 + cbs);
      float4 e1b = *(const float4*)(encW + 64 + cbs + 4);
      float4 e2a = *(const float4*)(encW + 128 + cbs);
      float4 e2b = *(const float4*)(encW + 128 + cbs + 4);
      float4 eba = *(const float4*)(encb + cbs);
      float4 ebb = *(const float4*)(encb + cbs + 4);
      float w0v[8] = {e0a.x,e0a.y,e0a.z,e0a.w,e0b.x,e0b.y,e0b.z,e0b.w};
      float w1v[8] = {e1a.x,e1a.y,e1a.z,e1a.w,e1b.x,e1b.y,e1b.z,e1b.w};
      float w2v[8] = {e2a.x,e2a.y,e2a.z,e2a.w,e2b.x,e2b.y,e2b.z,e2b.w};
      float bbv[8] = {eba.x,eba.y,eba.z,eba.w,ebb.x,ebb.y,ebb.z,ebb.w};
      float vv[8];
      #pragma unroll
      for (int j = 0; j < 8; j++)
        vv[j] = fmaf(x2, w2v[j], fmaf(x1, w1v[j], fmaf(x0, w0v[j], bbv[j])));
      pack8(vv, ah[kb], al[kb]);
    }
  }

  #pragma unroll
  for (int ct = 0; ct < 12; ct++) {
    f32x4 acc = (f32x4){0.f, 0.f, 0.f, 0.f};
    #pragma unroll
    for (int kb = 0; kb < 2; kb++) {
      int woff = (ct*16 + l15)*PK2 + kb*32 + quad*8;
      s16x8 bh = *(const s16x8*)(Wh + woff);
      s16x8 bl = *(const s16x8*)(Wl + woff);
      // bf16x3: drop al*bl (≤2^-18 relative ≈ 4e-6 per term)
      acc = __builtin_amdgcn_mfma_f32_16x16x32_bf16(al[kb], bh, acc, 0, 0, 0);
      acc = __builtin_amdgcn_mfma_f32_16x16x32_bf16(ah[kb], bl, acc, 0, 0, 0);
      acc = __builtin_amdgcn_mfma_f32_16x16x32_bf16(ah[kb], bh, acc, 0, 0, 0);
    }
    int j = ct*16 + l15;
    float* dst; int jj; float addv = 0.f;
    if (ct < 4)      { dst = P;  jj = j; addv = b1e[jj]; }
    else if (ct < 8) { dst = Q;  jj = j - 64; }
    else             { dst = Rb; jj = j - 128; }
    #pragma unroll
    for (int rr = 0; rr < 4; rr++) {
      int rw = base + quad*4 + rr;
      dst[(size_t)rw*64 + jj] = acc[rr] + addv;
    }
  }
}

// ------------- fused edge MLP + segment-reduce (grid 768) --------
// R17: direct-fragment gather (no staging LDS).
// R20: m2 scratch transposed to [col][row] (stride 36 f32, 144B = 16B-mult)
//      -> f32x4 LDS writes (4 consecutive rows, fixed col) and f32x4 reads
//      in the serial reduce. 16 vector LDS ops/lane-tile vs 64 scalar.
//      Reduce order unchanged -> values bit-identical.
__global__ __launch_bounds__(256, 3) void edge_fused_kernel(
    const float* __restrict__ Pbuf, const float* __restrict__ Qbuf,
    const int* __restrict__ psrc, const int* __restrict__ pdst,
    const ushort_t* __restrict__ W2hi, const ushort_t* __restrict__ W2lo,
    const float* __restrict__ b2,
    float* __restrict__ agg)
{
  __shared__ __align__(16) float m2s[4][64*36];
  __shared__ int sSDb[2][4][64];

  int tid = threadIdx.x;
  int lane = tid & 63, wave = tid >> 6;
  int l15 = lane & 15, quad = lane >> 4;

  float* m2 = m2s[wave];

  s16x8 w2h[2][4], w2l[2][4];
  #pragma unroll
  for (int kb = 0; kb < 2; kb++)
    #pragma unroll
    for (int ct = 0; ct < 4; ct++) {
      int off = (ct*16 + l15)*PK2 + kb*32 + quad*8;
      w2h[kb][ct] = *(const s16x8*)(W2hi + off);
      w2l[kb][ct] = *(const s16x8*)(W2lo + off);
    }
  float b2v[4];
  #pragma unroll
  for (int ct = 0; ct < 4; ct++) b2v[ct] = b2[ct*16 + l15];

  const int* tb = (lane < 32) ? psrc : pdst;
  int lidx = lane & 31;
  int step = gridDim.x * 128;
  int base0 = blockIdx.x * 128;

  int sidx = tb[base0 + wave*32 + lidx];
  sSDb[0][wave][lane] = sidx;

  int cb = 0;
  for (int base = base0; base < NEDGES; base += step) {
    const int* sc = sSDb[cb][wave];
    int nb = base + step;
    int havenext = nb < NEDGES;
    if (havenext) sidx = tb[nb + wave*32 + lidx];   // index prefetch

    // direct fragment gather + in-register hi/lo pack
    s16x8 pah[2][2], pal[2][2];     // [kb][rt]
    #pragma unroll
    for (int kb = 0; kb < 2; kb++) {
      float4 qq[2][2], pp[2][2];    // [rt][half] — 8 loads in flight per kb
      #pragma unroll
      for (int rt = 0; rt < 2; rt++) {
        int srow = sc[rt*16 + l15];
        int drow = sc[32 + rt*16 + l15];
        const float* qp = Qbuf + (((size_t)srow) << 6) + kb*32 + quad*8;
        const float* pd = Pbuf + (((size_t)drow) << 6) + kb*32 + quad*8;
        qq[rt][0] = *(const float4*)(qp);
        qq[rt][1] = *(const float4*)(qp + 4);
        pp[rt][0] = *(const float4*)(pd);
        pp[rt][1] = *(const float4*)(pd + 4);
      }
      #pragma unroll
      for (int rt = 0; rt < 2; rt++) {
        float vv[8];
        vv[0] = fmaxf(pp[rt][0].x + qq[rt][0].x, 0.f);
        vv[1] = fmaxf(pp[rt][0].y + qq[rt][0].y, 0.f);
        vv[2] = fmaxf(pp[rt][0].z + qq[rt][0].z, 0.f);
        vv[3] = fmaxf(pp[rt][0].w + qq[rt][0].w, 0.f);
        vv[4] = fmaxf(pp[rt][1].x + qq[rt][1].x, 0.f);
        vv[5] = fmaxf(pp[rt][1].y + qq[rt][1].y, 0.f);
        vv[6] = fmaxf(pp[rt][1].z + qq[rt][1].z, 0.f);
        vv[7] = fmaxf(pp[rt][1].w + qq[rt][1].w, 0.f);
        pack8(vv, pah[kb][rt], pal[kb][rt]);
      }
    }

    f32x4 facc[2][4];
    #pragma unroll
    for (int rt = 0; rt < 2; rt++)
      #pragma unroll
      for (int ct = 0; ct < 4; ct++)
        facc[rt][ct] = (f32x4){0.f, 0.f, 0.f, 0.f};

    #pragma unroll
    for (int kb = 0; kb < 2; kb++)
      #pragma unroll
      for (int ct = 0; ct < 4; ct++)
        #pragma unroll
        for (int rt = 0; rt < 2; rt++) {
          // bf16x3: drop pal*w2l
          facc[rt][ct] = __builtin_amdgcn_mfma_f32_16x16x32_bf16(pal[kb][rt], w2h[kb][ct], facc[rt][ct], 0, 0, 0);
          facc[rt][ct] = __builtin_amdgcn_mfma_f32_16x16x32_bf16(pah[kb][rt], w2l[kb][ct], facc[rt][ct], 0, 0, 0);
          facc[rt][ct] = __builtin_amdgcn_mfma_f32_16x16x32_bf16(pah[kb][rt], w2h[kb][ct], facc[rt][ct], 0, 0, 0);
        }

    // stage next tile's indices during m2-write + reduce + atomics
    if (havenext) sSDb[cb ^ 1][wave][lane] = sidx;

    // transposed m2 write: lane's 4 consecutive rows at fixed col -> f32x4
    #pragma unroll
    for (int rt = 0; rt < 2; rt++)
      #pragma unroll
      for (int ct = 0; ct < 4; ct++) {
        f32x4 w;
        #pragma unroll
        for (int r = 0; r < 4; r++)
          w[r] = fmaxf(facc[rt][ct][r] + b2v[ct], 0.f);
        *(f32x4*)&m2[(ct*16 + l15)*36 + rt*16 + quad*4] = w;
      }

    // serial 32-row segment reduce (same order as before; f32x4 column reads)
    int curd = sc[32];
    float acc = 0.f;
    const float* mcol = &m2[lane*36];
    #pragma unroll
    for (int c4 = 0; c4 < 8; c4++) {
      f32x4 v4 = *(const f32x4*)(mcol + c4*4);
      #pragma unroll
      for (int r = 0; r < 4; r++) {
        int d = sc[32 + c4*4 + r];
        if (d != curd) {
          unsafeAtomicAdd(&agg[((size_t)curd << 6) + lane], acc);
          acc = 0.f; curd = d;
        }
        acc += v4[r];
      }
    }
    unsafeAtomicAdd(&agg[((size_t)curd << 6) + lane], acc);

    cb ^= 1;
  }
}

// ------------- node MLP -------------
__global__ __launch_bounds__(256) void node_mfma_kernel(
    const float* __restrict__ aggF, const float* __restrict__ Rbuf,
    const ushort_t* __restrict__ W1h, const ushort_t* __restrict__ W1l,
    const float* __restrict__ b1,
    const ushort_t* __restrict__ W2h, const ushort_t* __restrict__ W2l,
    const float* __restrict__ b2,
    float* __restrict__ uout, float* __restrict__ sA, float* __restrict__ sB)
{
  __shared__ __align__(16) ushort_t sMh[4][16*PK2];
  __shared__ __align__(16) ushort_t sMl[4][16*PK2];
  int tid = threadIdx.x, lane = tid & 63, wave = tid >> 6;
  int l15 = lane & 15, quad = lane >> 4;
  int base = blockIdx.x * 64 + wave * 16;
  int g = blockIdx.x >> 5;

  s16x8 ah[2], al[2];
  {
    int em = base + l15;
    #pragma unroll
    for (int kb = 0; kb < 2; kb++) {
      size_t off = (size_t)em*64 + kb*32 + quad*8;
      float4 v0 = *(const float4*)(aggF + off);
      float4 v1 = *(const float4*)(aggF + off + 4);
      float vv[8] = {v0.x,v0.y,v0.z,v0.w,v1.x,v1.y,v1.z,v1.w};
      pack8(vv, ah[kb], al[kb]);
    }
  }

  ushort_t* mh = sMh[wave];
  ushort_t* ml = sMl[wave];
  float b1v[4], b2v[4];
  #pragma unroll
  for (int ct = 0; ct < 4; ct++) { b1v[ct] = b1[ct*16+l15]; b2v[ct] = b2[ct*16+l15]; }

  #pragma unroll
  for (int ct = 0; ct < 4; ct++) {
    f32x4 acc = (f32x4){0.f, 0.f, 0.f, 0.f};
    #pragma unroll
    for (int kb = 0; kb < 2; kb++) {
      int woff = (ct*16 + l15)*PK2 + kb*32 + quad*8;
      s16x8 bh = *(const s16x8*)(W1h + woff);
      s16x8 bl = *(const s16x8*)(W1l + woff);
      // bf16x3: drop al*bl
      acc = __builtin_amdgcn_mfma_f32_16x16x32_bf16(al[kb], bh, acc, 0, 0, 0);
      acc = __builtin_amdgcn_mfma_f32_16x16x32_bf16(ah[kb], bl, acc, 0, 0, 0);
      acc = __builtin_amdgcn_mfma_f32_16x16x32_bf16(ah[kb], bh, acc, 0, 0, 0);
    }
    int j = ct*16 + l15;
    #pragma unroll
    for (int rr = 0; rr < 4; rr += 2) {
      int row = quad*4 + rr;
      float v0 = fmaxf(acc[rr]   + Rbuf[(size_t)(base+row)*64   + j] + b1v[ct], 0.f);
      float v1 = fmaxf(acc[rr+1] + Rbuf[(size_t)(base+row+1)*64 + j] + b1v[ct], 0.f);
      unsigned int ph, pl;
      pack2(v0, v1, ph, pl);
      mh[row*PK2 + j]     = (ushort_t)(ph & 0xffffu);
      mh[(row+1)*PK2 + j] = (ushort_t)(ph >> 16);
      ml[row*PK2 + j]     = (ushort_t)(pl & 0xffffu);
      ml[(row+1)*PK2 + j] = (ushort_t)(pl >> 16);
    }
  }

  s16x8 mhf[2], mlf[2];
  #pragma unroll
  for (int kb = 0; kb < 2; kb++) {
    int idx = l15*PK2 + kb*32 + quad*8;
    mhf[kb] = *(const s16x8*)&mh[idx];
    mlf[kb] = *(const s16x8*)&ml[idx];
  }
  #pragma unroll
  for (int ct = 0; ct < 4; ct++) {
    f32x4 facc = (f32x4){0.f, 0.f, 0.f, 0.f};
    #pragma unroll
    for (int kb = 0; kb < 2; kb++) {
      int woff = (ct*16 + l15)*PK2 + kb*32 + quad*8;
      s16x8 bh = *(const s16x8*)(W2h + woff);
      s16x8 bl = *(const s16x8*)(W2l + woff);
      // bf16x3: drop mlf*bl
      facc = __builtin_amdgcn_mfma_f32_16x16x32_bf16(mlf[kb], bh, facc, 0, 0, 0);
      facc = __builtin_amdgcn_mfma_f32_16x16x32_bf16(mhf[kb], bl, facc, 0, 0, 0);
      facc = __builtin_amdgcn_mfma_f32_16x16x32_bf16(mhf[kb], bh, facc, 0, 0, 0);
    }
    int j = ct*16 + l15;
    float s = 0.f, s2 = 0.f;
    #pragma unroll
    for (int rr = 0; rr < 4; rr++) {
      int row = quad*4 + rr;
      float v = fmaxf(facc[rr] + b2v[ct], 0.f);
      uout[(size_t)(base+row)*64 + j] = v;
      s += v; s2 += v*v;
    }
    s  += __shfl_xor(s, 16);  s  += __shfl_xor(s, 32);
    s2 += __shfl_xor(s2, 16); s2 += __shfl_xor(s2, 32);
    if (quad == 0) {
      unsafeAtomicAdd(&sA[g*64 + j], s);
      unsafeAtomicAdd(&sB[g*64 + j], s2);
    }
  }
}

// ------------- decoder -------------
__global__ __launch_bounds__(64) void decoder_kernel(
    const float* __restrict__ u, const float* __restrict__ sA,
    const float* __restrict__ sB, const float* __restrict__ W,
    const float* __restrict__ b, float* __restrict__ X)
{
  __shared__ float sh[64][65];
  __shared__ float sm[64], sr[64];
  int lane = threadIdx.x;
  int nb = blockIdx.x * 64;
  int g = blockIdx.x >> 5;
  {
    float a = sA[g*64 + lane], q = sB[g*64 + lane];
    float mean = a * (1.f / NSAMP);
    float var = q * (1.f / NSAMP) - mean * mean;
    sm[lane] = mean;
    sr[lane] = rsqrtf(var + EPS);
  }
  for (int r = 0; r < 64; r++) sh[r][lane] = u[(size_t)(nb + r) * 64 + lane];
  __syncthreads();
  float a0 = b[0], a1 = b[1], a2 = b[2];
  #pragma unroll
  for (int c = 0; c < 64; c++) {
    float v = (sh[lane][c] - sm[c]) * sr[c];
    a0 = fmaf(v, W[c*3+0], a0);
    a1 = fmaf(v, W[c*3+1], a1);
    a2 = fmaf(v, W[c*3+2], a2);
  }
  float inv = 1.f / sqrtf(a0*a0 + a1*a1 + a2*a2);
  int n = nb + lane;
  X[n*3+0] = a0 * inv;
  X[n*3+1] = a1 * inv;
  X[n*3+2] = a2 * inv;
}

// ------------- MMD: R16 register-blocked kXX (8 m-points/thread) ----------
__device__ inline float block_reduce_sum(float v) {
  #pragma unroll
  for (int o = 32; o > 0; o >>= 1) v += __shfl_down(v, o, 64);
  __shared__ float red[4];
  int lane = threadIdx.x & 63, w = threadIdx.x >> 6;
  if (lane == 0) red[w] = v;
  __syncthreads();
  float t = 0.f;
  if (threadIdx.x == 0) t = red[0] + red[1] + red[2] + red[3];
  return t;
}

__global__ __launch_bounds__(256) void mmd_kernel(
    const float* __restrict__ X, YArr Y,
    float* __restrict__ kxx, float* __restrict__ kxy)
{
  if (blockIdx.x < 512) {
    int b  = blockIdx.x >> 5;
    int nt = blockIdx.x & 31;
    const float* Xb = X + (size_t)b * NSAMP * 3;
    __shared__ float sx[192];
    if (threadIdx.x < 192) sx[threadIdx.x] = Xb[nt*192 + threadIdx.x];
    __syncthreads();
    float mx0[8], mx1[8], mx2[8], ac[8];
    #pragma unroll
    for (int k = 0; k < 8; k++) {
      int m = k*256 + threadIdx.x;
      mx0[k] = Xb[m*3+0]; mx1[k] = Xb[m*3+1]; mx2[k] = Xb[m*3+2];
      ac[k] = 0.f;
    }
    for (int n = 0; n < 64; n++) {
      float s0 = sx[n*3+0], s1 = sx[n*3+1], s2 = sx[n*3+2];
      #pragma unroll
      for (int k = 0; k < 8; k++) {
        float d = fmaf(mx2[k], s2, fmaf(mx1[k], s1, mx0[k]*s0));
        ac[k] += __expf(2.f*d - 2.f);
      }
    }
    float ps = ((ac[0]+ac[1])+(ac[2]+ac[3])) + ((ac[4]+ac[5])+(ac[6]+ac[7]));
    float t2 = block_reduce_sum(ps);
    if (threadIdx.x == 0) atomicAdd(&kxx[b], t2);
  } else {
    int t  = blockIdx.x - 512;
    int b  = t >> 2;
    int ms = t & 3;
    const float* Xb = X + (size_t)b * NSAMP * 3;
    float ps = 0.f;
    #pragma unroll
    for (int it = 0; it < 2; it++) {
      int n = ms*512 + it*256 + threadIdx.x;
      float x0 = Xb[n*3+0], x1 = Xb[n*3+1], x2 = Xb[n*3+2];
      #pragma unroll
      for (int m = 0; m < 64; m++) {
        float d = x0*Y.v[m*3+0] + x1*Y.v[m*3+1] + x2*Y.v[m*3+2];
        ps += __expf(2.f*d - 2.f);
      }
    }
    float t2 = block_reduce_sum(ps);
    if (threadIdx.x == 0) atomicAdd(&kxy[b], t2);
  }
}

__global__ void loss_kernel(const float* __restrict__ kxx,
                            const float* __restrict__ kxy,
                            float kyy, float* __restrict__ out)
{
  if (threadIdx.x == 0 && blockIdx.x == 0) {
    float s = 0.f;
    for (int b = 0; b < NBATCH; b++)
      s += kxx[b] * (1.0f/((float)NSAMP*(float)NSAMP))
         - 2.0f * kxy[b] * (1.0f/((float)NSAMP*64.0f));
    out[0] = s * (1.0f/NBATCH) + kyy;
  }
}

// ------------- launch -------------
extern "C" void kernel_launch(void* const* d_in, const int* in_sizes, int n_in,
                              void* d_out, int out_size, void* d_ws, size_t ws_size,
                              hipStream_t stream)
{
  const float* x    = (const float*)d_in[0];
  const int*   esrc = (const int*)  d_in[1];
  const int*   edst = (const int*)  d_in[2];
  const float* encW = (const float*)d_in[4];
  const float* encb = (const float*)d_in[5];
  const float* m1W  = (const float*)d_in[6];
  const float* m1b  = (const float*)d_in[7];
  const float* m2W  = (const float*)d_in[8];
  const float* m2b  = (const float*)d_in[9];
  const float* u1W  = (const float*)d_in[10];
  const float* u1b  = (const float*)d_in[11];
  const float* u2W  = (const float*)d_in[12];
  const float* u2b  = (const float*)d_in[13];
  const float* decW = (const float*)d_in[14];
  const float* decb = (const float*)d_in[15];
  float* out = (float*)d_out;

  const size_t NF = (size_t)NNODES * 64;
  // single zero region: [aggAll | statsA | statsB | kxx | kxy | icnt]
  float* aggAll = (float*)d_ws;        // 4 * NF
  float* statsA = aggAll + 4*NF;       // 4096
  float* statsB = statsA + 4096;       // 4096
  float* kxx    = statsB + 4096;       // 16
  float* kxy    = kxx + 16;            // 16 (zeroed; atomicAdd target)
  int*   icnt   = (int*)(kxy + 16);    // 32768
  size_t zero_bytes = (4*NF + 4096 + 4096 + 32) * sizeof(float) + NNODES * sizeof(int);

  float* u_buf  = (float*)(icnt + NNODES);
  float* Pbuf   = u_buf + NF;
  float* Qbuf   = Pbuf + NF;
  float* Rbuf   = Qbuf + NF;
  int* ioffs    = (int*)(Rbuf + NF + 16);   // +16 pad keeps legacy layout offsets
  int* icur     = ioffs + NNODES;
  int* psrc     = icur + NNODES;
  int* pdst     = psrc + NEDGES;
  ushort_t* us  = (ushort_t*)(pdst + NEDGES);
  ushort_t* wc_hi  = us;  us += 4*192*PK2;
  ushort_t* wc_lo  = us;  us += 4*192*PK2;
  ushort_t* w1b_hi = us;  us += 4*64*PK2;
  ushort_t* w1b_lo = us;  us += 4*64*PK2;
  ushort_t* w2e_hi = us;  us += 4*64*PK2;
  ushort_t* w2e_lo = us;  us += 4*64*PK2;
  ushort_t* w2n_hi = us;  us += 4*64*PK2;
  ushort_t* w2n_lo = us;  us += 4*64*PK2;

  float* X = out + 1;

  hipMemsetAsync(aggAll, 0, zero_bytes, stream);

  setup_kernel<<<384 + NEDGES/256, 256, 0, stream>>>(
      m1W, m2W, u1W, u2W,
      wc_hi, wc_lo, w1b_hi, w1b_lo, w2e_hi, w2e_lo, w2n_hi, w2n_lo,
      edst, icnt);
  scan_kernel<<<1, 1024, 0, stream>>>(icnt, ioffs, icur);
  fill_kernel<<<NEDGES/256, 256, 0, stream>>>(esrc, edst, icur, psrc, pdst);

  for (int l = 0; l < 4; l++) {
    const ushort_t* wch = wc_hi + (size_t)l*192*PK2;
    const ushort_t* wcl = wc_lo + (size_t)l*192*PK2;
    if (l == 0)
      norm_pqr_kernel<0><<<512, 256, 0, stream>>>(
          x, nullptr, nullptr, encW, encb, wch, wcl, m1b + l*64,
          Pbuf, Qbuf, Rbuf);
    else
      norm_pqr_kernel<1><<<512, 256, 0, stream>>>(
          u_buf, statsA + (l-1)*1024, statsB + (l-1)*1024, nullptr, nullptr,
          wch, wcl, m1b + l*64, Pbuf, Qbuf, Rbuf);

    edge_fused_kernel<<<768, 256, 0, stream>>>(
        Pbuf, Qbuf, psrc, pdst,
        w2e_hi + (size_t)l*64*PK2, w2e_lo + (size_t)l*64*PK2, m2b + l*64,
        aggAll + (size_t)l*NF);

    node_mfma_kernel<<<512, 256, 0, stream>>>(
        aggAll + (size_t)l*NF, Rbuf,
        w1b_hi + (size_t)l*64*PK2, w1b_lo + (size_t)l*64*PK2, u1b + l*64,
        w2n_hi + (size_t)l*64*PK2, w2n_lo + (size_t)l*64*PK2, u2b + l*64,
        u_buf, statsA + l*1024, statsB + l*1024);
  }

  decoder_kernel<<<NNODES/64, 64, 0, stream>>>(
      u_buf, statsA + 3*1024, statsB + 3*1024, decW, decb, X);

  YArr Y;
  {
    const double pi = 3.14159265358979323846;
    double phi = pi * (3.0 - sqrt(5.0));
    for (int i = 0; i < 64; i++) {
      double y  = 1.0 - 2.0 * (double)i / 63.0;
      double r  = sqrt(fmax(0.0, 1.0 - y*y));
      double th = phi * (double)i;
      Y.v[i*3+0] = (float)(cos(th) * r);
      Y.v[i*3+1] = (float)y;
      Y.v[i*3+2] = (float)(sin(th) * r);
    }
  }
  double kyy_acc = 0.0;
  for (int i = 0; i < 64; i++)
    for (int j = 0; j < 64; j++) {
      double d = (double)Y.v[i*3+0]*Y.v[j*3+0]
               + (double)Y.v[i*3+1]*Y.v[j*3+1]
               + (double)Y.v[i*3+2]*Y.v[j*3+2];
      kyy_acc += exp(2.0*d - 2.0);
    }
  float kyy = (float)(kyy_acc / 4096.0);

  mmd_kernel<<<512 + 64, 256, 0, stream>>>(X, Y, kxx, kxy);
  loss_kernel<<<1, 64, 0, stream>>>(kxx, kxy, kyy, out);
}